// Round 10
// baseline (752.643 us; speedup 1.0000x reference)
//
#include <hip/hip_runtime.h>

#define NP 500000
#define NA 25000

// native-rcp tanh: exp + v_rcp (~1ulp) instead of IEEE divide expansion
__device__ __forceinline__ float tanh_fast(float x) {
    float e = __expf(2.0f * x);
    return 1.0f - __fdividef(2.0f, e + 1.0f);
}

// readlane with float bitcast (__builtin_amdgcn_readlane is (int,int);
// passing float value-converts = truncates — the R2/R3 bug).
__device__ __forceinline__ float readlane_f(float v, int lane) {
    int iv = __builtin_bit_cast(int, v);
    int r = __builtin_amdgcn_readlane(iv, lane);
    return __builtin_bit_cast(float, r);
}

// Sum over each consecutive 8-lane group, all in VALU (DPP), no LDS.
__device__ __forceinline__ float dpp8_reduce(float s) {
    int x;
    x = __builtin_amdgcn_update_dpp(0, __builtin_bit_cast(int, s), 0xB1, 0xF, 0xF, true);
    s += __builtin_bit_cast(float, x);
    x = __builtin_amdgcn_update_dpp(0, __builtin_bit_cast(int, s), 0x4E, 0xF, 0xF, true);
    s += __builtin_bit_cast(float, x);
    x = __builtin_amdgcn_update_dpp(0, __builtin_bit_cast(int, s), 0x141, 0xF, 0xF, true);
    s += __builtin_bit_cast(float, x);
    return s;
}

__device__ __forceinline__ unsigned short f2bf(float x) {
    union { float f; unsigned int u; } c; c.f = x;
    unsigned int r = c.u + 0x7FFFu + ((c.u >> 16) & 1u);
    return (unsigned short)(r >> 16);
}
__device__ __forceinline__ float bf2f(unsigned short h) {
    union { unsigned int u; float f; } c; c.u = ((unsigned int)h) << 16;
    return c.f;
}
__device__ __forceinline__ unsigned int pack2bf(float a, float b) {
    return (unsigned int)f2bf(a) | ((unsigned int)f2bf(b) << 16);
}
__device__ __forceinline__ float lo_bf(unsigned int x) { return bf2f((unsigned short)(x & 0xffffu)); }
__device__ __forceinline__ float hi_bf(unsigned int x) { return bf2f((unsigned short)(x >> 16)); }
__device__ __forceinline__ float lo_bf_f(unsigned int x) {
    return __builtin_bit_cast(float, x << 16);
}
__device__ __forceinline__ float hi_bf_f(unsigned int x) {
    return __builtin_bit_cast(float, x & 0xffff0000u);
}

// ---------------------------------------------------------------------------
// K0a: 16 atoms/block.  u = p1 @ W_pi[0:64,:] + b_pi  (f32 [atom][col])
//      v = p1 @ W_pi[64:128,:] -> vq[atom][l*8 + 0..3]  (bf16, col = 64q+l)
// ---------------------------------------------------------------------------
extern "C" __global__ __launch_bounds__(256, 2)
void k0_uv(const float* __restrict__ p1,
           const float* __restrict__ W_pi,
           const float* __restrict__ b_pi,
           float* __restrict__ u,
           unsigned short* __restrict__ vq)
{
    __shared__ float sW[32 * 256];     // 32 KB
    __shared__ float sp1[16 * 64];     //  4 KB

    const int t = threadIdx.x;
    const int wv = t >> 6;
    const int l = t & 63;
    const int atom0 = blockIdx.x * 16;

    #pragma unroll
    for (int f = 0; f < 4; ++f) {
        int idx = f * 256 + t;
        int at = atom0 + (idx >> 6);
        int atc = at < NA ? at : NA - 1;
        sp1[idx] = p1[(size_t)atc * 64 + (idx & 63)];
    }

    float accu[4][4] = {{0}}, accv[4][4] = {{0}};

    #pragma unroll
    for (int s = 0; s < 4; ++s) {
        __syncthreads();
        {
            const float4* src = (const float4*)(W_pi + s * 32 * 256);
            float4* dst = (float4*)sW;
            #pragma unroll
            for (int f = 0; f < 8; ++f) dst[f * 256 + t] = src[f * 256 + t];
        }
        __syncthreads();
        const int kbase = (s & 1) * 32;
        #pragma unroll 2
        for (int k = 0; k < 32; ++k) {
            float wq[4];
            #pragma unroll
            for (int q = 0; q < 4; ++q) wq[q] = sW[k * 256 + 64 * q + l];
            #pragma unroll
            for (int a = 0; a < 4; ++a) {
                float pv = sp1[(wv * 4 + a) * 64 + kbase + k];
                #pragma unroll
                for (int q = 0; q < 4; ++q) {
                    if (s < 2) accu[a][q] = fmaf(pv, wq[q], accu[a][q]);
                    else       accv[a][q] = fmaf(pv, wq[q], accv[a][q]);
                }
            }
        }
    }

    #pragma unroll
    for (int a = 0; a < 4; ++a) {
        const int at = atom0 + wv * 4 + a;
        if (at < NA) {
            #pragma unroll
            for (int q = 0; q < 4; ++q)
                u[(size_t)at * 256 + 64 * q + l] = accu[a][q] + b_pi[64 * q + l];
            uint2 vv;
            vv.x = pack2bf(accv[a][0], accv[a][1]);
            vv.y = pack2bf(accv[a][2], accv[a][3]);
            *(uint2*)&vq[(size_t)at * 512 + 8 * l] = vv;
        }
    }
}

// ---------------------------------------------------------------------------
// K0b (+fused pair count): qi = p3 @ wi_pix -> qi_bf[atom][4l+x];
//                          qj = p3 @ wj_pix -> vq[atom][8l+4..6]
// ---------------------------------------------------------------------------
extern "C" __global__ __launch_bounds__(256, 4)
void k0_q(const float* __restrict__ p3,
          const float* __restrict__ wi_pix,
          const float* __restrict__ wj_pix,
          const int* __restrict__ ind2,
          int* __restrict__ cnt,
          unsigned short* __restrict__ qi_bf,
          unsigned short* __restrict__ vq)
{
    __shared__ float sWi[64 * 64];
    __shared__ float sWj[64 * 64];

    const int t = threadIdx.x;

    // fused k_count: first 1954 blocks also count pairs
    {
        int gp = blockIdx.x * 256 + t;
        if (gp < NP) atomicAdd(&cnt[ind2[2 * gp]], 1);
    }

    {
        const float4* si = (const float4*)wi_pix;
        const float4* sj = (const float4*)wj_pix;
        float4* di = (float4*)sWi;
        float4* dj = (float4*)sWj;
        #pragma unroll
        for (int f = 0; f < 4; ++f) { di[f * 256 + t] = si[f * 256 + t]; dj[f * 256 + t] = sj[f * 256 + t]; }
    }
    __syncthreads();

    const int w = t >> 6;
    const int l = t & 63;
    const int atom = blockIdx.x * 4 + w;     // grid 6250 -> < 25000

    float val0 = p3[((size_t)atom * 3 + 0) * 64 + l];
    float val1 = p3[((size_t)atom * 3 + 1) * 64 + l];
    float val2 = p3[((size_t)atom * 3 + 2) * 64 + l];

    float ai[3] = {0, 0, 0}, aj[3] = {0, 0, 0};
    #pragma unroll 8
    for (int k = 0; k < 64; ++k) {
        float a0 = readlane_f(val0, k);
        float a1 = readlane_f(val1, k);
        float a2 = readlane_f(val2, k);
        float wi = sWi[k * 64 + l];
        float wj = sWj[k * 64 + l];
        ai[0] = fmaf(a0, wi, ai[0]); aj[0] = fmaf(a0, wj, aj[0]);
        ai[1] = fmaf(a1, wi, ai[1]); aj[1] = fmaf(a1, wj, aj[1]);
        ai[2] = fmaf(a2, wi, ai[2]); aj[2] = fmaf(a2, wj, aj[2]);
    }
    uint2 iu, ju;
    iu.x = pack2bf(ai[0], ai[1]); iu.y = pack2bf(ai[2], 0.0f);
    ju.x = pack2bf(aj[0], aj[1]); ju.y = pack2bf(aj[2], 0.0f);
    *(uint2*)&qi_bf[(size_t)atom * 256 + 4 * l] = iu;
    *(uint2*)&vq[(size_t)atom * 512 + 8 * l + 4] = ju;
}

// ---------------------------------------------------------------------------
// CSR build
// ---------------------------------------------------------------------------
extern "C" __global__ __launch_bounds__(1024)
void csr_scan(const int* __restrict__ cnt, int* __restrict__ rowstart)
{
    __shared__ int ssum[1024];
    const int t = threadIdx.x;
    const int base = t * 25;

    int s = 0;
    #pragma unroll 5
    for (int i = 0; i < 25; ++i) {
        int idx = base + i;
        s += (idx < NA) ? cnt[idx] : 0;
    }
    ssum[t] = s;
    __syncthreads();
    for (int off = 1; off < 1024; off <<= 1) {
        int vv = (t >= off) ? ssum[t - off] : 0;
        __syncthreads();
        ssum[t] += vv;
        __syncthreads();
    }
    int run = (t > 0) ? ssum[t - 1] : 0;
    for (int i = 0; i < 25; ++i) {
        int idx = base + i;
        if (idx <= NA) rowstart[idx] = run;
        run += (idx < NA) ? cnt[idx] : 0;
    }
}

// k_scatter: emit 64B pair record in CSR slot order:
// rec[0]=p(bits) rec[1]=jj(bits) rec[2..4]=d3 rec[5..12]=basis[0..7] rec[13..15]=pad
extern "C" __global__ void k_scatter(const int* __restrict__ ind2,
                                     const float* __restrict__ d3,
                                     const float* __restrict__ basis,
                                     const int* __restrict__ rowstart,
                                     int* __restrict__ cursor,
                                     float* __restrict__ prec)
{
    int p = blockIdx.x * 256 + threadIdx.x;
    if (p < NP) {
        int ii = ind2[2 * p];
        int jj = ind2[2 * p + 1];
        int pos = atomicAdd(&cursor[ii], 1);
        float* r = prec + (size_t)(rowstart[ii] + pos) * 16;
        float4 b0 = *(const float4*)&basis[(size_t)p * 8];
        float4 b1 = *(const float4*)&basis[(size_t)p * 8 + 4];
        float4 r0;
        r0.x = __builtin_bit_cast(float, p);
        r0.y = __builtin_bit_cast(float, jj);
        r0.z = d3[3 * (size_t)p + 0];
        r0.w = d3[3 * (size_t)p + 1];
        float4 r1;
        r1.x = d3[3 * (size_t)p + 2];
        r1.y = b0.x; r1.z = b0.y; r1.w = b0.z;
        float4 r2;
        r2.x = b0.w; r2.y = b1.x; r2.z = b1.y; r2.w = b1.z;
        float4 r3;
        r3.x = b1.w; r3.y = 0; r3.z = 0; r3.w = 0;
        *(float4*)&r[0]  = r0;
        *(float4*)&r[4]  = r1;
        *(float4*)&r[8]  = r2;
        *(float4*)&r[12] = r3;
    }
}

// ---------------------------------------------------------------------------
// K_pair: wave per atom; 2 pairs/iter; sequential 64B records; 3-stage
// pipeline: U=compute-ready, M=rec-ready + vq in flight, R=rec in flight.
// No rec->vq dependent wait inside one iteration.
// ---------------------------------------------------------------------------
extern "C" __global__ __launch_bounds__(256, 4)
void k_pair(const float* __restrict__ prec,
            const float* __restrict__ W_ii,
            const float* __restrict__ u,
            const unsigned short* __restrict__ vq,
            const unsigned short* __restrict__ qi_bf,
            const int* __restrict__ rowstart,
            float* __restrict__ out_i1,
            float* __restrict__ out_ix,
            float* __restrict__ p1_agg,
            float* __restrict__ p3_agg)
{
    const int t = threadIdx.x;
    const int w = t >> 6;
    const int l = t & 63;
    const int n = blockIdx.x * 4 + w;        // grid 6250*4 = 25000 exactly
    const int lb = l & 7;

    // W_ii columns l (lo) and 64+l (hi) packed as bf16 pairs: 32 VGPRs
    unsigned int wAB[32];
    #pragma unroll
    for (int c = 0; c < 32; ++c)
        wAB[c] = pack2bf(W_ii[c * 128 + l], W_ii[c * 128 + 64 + l]);

    float uu[4];
    #pragma unroll
    for (int q = 0; q < 4; ++q) uu[q] = u[(size_t)n * 256 + 64 * q + l];
    float qiv[3];
    {
        uint2 iu = *(const uint2*)&qi_bf[(size_t)n * 256 + 4 * l];
        qiv[0] = lo_bf(iu.x); qiv[1] = hi_bf(iu.x); qiv[2] = lo_bf(iu.y);
    }

    const int start = rowstart[n];
    const int end   = rowstart[n + 1];

    float agg1a = 0.0f, agg1b = 0.0f;
    float agg30 = 0.0f, agg31 = 0.0f, agg32 = 0.0f;

    if (start < end) {
        const int last = end - 1;
        auto clampi = [&](int i) { return i <= last ? i : last; };

        // --- unit registers ---
        // U stage (compute): full data
        int   Up0, Up1;            // p
        float Ud0x, Ud0y, Ud0z, Ud1x, Ud1y, Ud1z;
        float Ubs0, Ubs1;
        uint4 Uvq0, Uvq1;
        // M stage: record fields ready, vq in flight (dest = Mvq)
        int   Mp0, Mp1, Mj0, Mj1;
        float Md0x, Md0y, Md0z, Md1x, Md1y, Md1z;
        float Mbs0, Mbs1;
        uint4 Mvq0, Mvq1;

        // prologue: load U recs, issue U vq; load M recs, issue M vq
        {
            const float4* r0 = (const float4*)&prec[(size_t)clampi(start) * 16];
            const float4* r1 = (const float4*)&prec[(size_t)clampi(start + 1) * 16];
            float4 a0 = r0[0], a1 = r1[0];
            Up0 = __builtin_bit_cast(int, a0.x);
            int Uj0 = __builtin_bit_cast(int, a0.y);
            Ud0x = a0.z; Ud0y = a0.w;
            Ud0z = ((const float*)r0)[4];
            Ubs0 = ((const float*)r0)[5 + lb];
            Up1 = __builtin_bit_cast(int, a1.x);
            int Uj1 = __builtin_bit_cast(int, a1.y);
            Ud1x = a1.z; Ud1y = a1.w;
            Ud1z = ((const float*)r1)[4];
            Ubs1 = ((const float*)r1)[5 + lb];
            Uvq0 = *(const uint4*)&vq[(size_t)Uj0 * 512 + 8 * l];
            Uvq1 = *(const uint4*)&vq[(size_t)Uj1 * 512 + 8 * l];

            const float4* m0 = (const float4*)&prec[(size_t)clampi(start + 2) * 16];
            const float4* m1 = (const float4*)&prec[(size_t)clampi(start + 3) * 16];
            float4 b0 = m0[0], b1 = m1[0];
            Mp0 = __builtin_bit_cast(int, b0.x);
            Mj0 = __builtin_bit_cast(int, b0.y);
            Md0x = b0.z; Md0y = b0.w;
            Md0z = ((const float*)m0)[4];
            Mbs0 = ((const float*)m0)[5 + lb];
            Mp1 = __builtin_bit_cast(int, b1.x);
            Mj1 = __builtin_bit_cast(int, b1.y);
            Md1x = b1.z; Md1y = b1.w;
            Md1z = ((const float*)m1)[4];
            Mbs1 = ((const float*)m1)[5 + lb];
            Mvq0 = *(const uint4*)&vq[(size_t)Mj0 * 512 + 8 * l];
            Mvq1 = *(const uint4*)&vq[(size_t)Mj1 * 512 + 8 * l];
        }

        for (int it = start; it < end; it += 2) {
            // --- issue R-stage record loads (it+4, it+5): sequential stream ---
            const float4* r0 = (const float4*)&prec[(size_t)clampi(it + 4) * 16];
            const float4* r1 = (const float4*)&prec[(size_t)clampi(it + 5) * 16];
            float4 ra = r0[0];
            float  rz0 = ((const float*)r0)[4];
            float  rb0 = ((const float*)r0)[5 + lb];
            float4 rb = r1[0];
            float  rz1 = ((const float*)r1)[4];
            float  rb1 = ((const float*)r1)[5 + lb];

            // ---- compute U (vq issued ≥1 iteration ago) ----
            float h00 = tanh_fast(uu[0] + lo_bf(Uvq0.x));
            float h10 = tanh_fast(uu[0] + lo_bf(Uvq1.x));
            float h01 = tanh_fast(uu[1] + hi_bf(Uvq0.x));
            float h11 = tanh_fast(uu[1] + hi_bf(Uvq1.x));
            float h02 = tanh_fast(uu[2] + lo_bf(Uvq0.y));
            float h12 = tanh_fast(uu[2] + lo_bf(Uvq1.y));
            float h03 = tanh_fast(uu[3] + hi_bf(Uvq0.y));
            float h13 = tanh_fast(uu[3] + hi_bf(Uvq1.y));

            float pre0[4], pre1[4];
            pre0[0] = dpp8_reduce(h00 * Ubs0);
            pre1[0] = dpp8_reduce(h10 * Ubs1);
            pre0[1] = dpp8_reduce(h01 * Ubs0);
            pre1[1] = dpp8_reduce(h11 * Ubs1);
            pre0[2] = dpp8_reduce(h02 * Ubs0);
            pre1[2] = dpp8_reduce(h12 * Ubs1);
            pre0[3] = dpp8_reduce(h03 * Ubs0);
            pre1[3] = dpp8_reduce(h13 * Ubs1);

            float a0A = 0, a0B = 0, a1A = 0, a1B = 0;
            float b0A = 0, b0B = 0, b1A = 0, b1B = 0;
            #pragma unroll
            for (int c = 0; c < 32; c += 2) {
                float p00 = readlane_f(pre0[c >> 3], 8 * (c & 7));
                float p10 = readlane_f(pre1[c >> 3], 8 * (c & 7));
                float p01 = readlane_f(pre0[(c + 1) >> 3], 8 * ((c + 1) & 7));
                float p11 = readlane_f(pre1[(c + 1) >> 3], 8 * ((c + 1) & 7));
                float wlo0 = lo_bf_f(wAB[c]), whi0 = hi_bf_f(wAB[c]);
                float wlo1 = lo_bf_f(wAB[c + 1]), whi1 = hi_bf_f(wAB[c + 1]);
                a0A = fmaf(p00, wlo0, a0A);  b0A = fmaf(p00, whi0, b0A);
                a1A = fmaf(p10, wlo0, a1A);  b1A = fmaf(p10, whi0, b1A);
                a0B = fmaf(p01, wlo1, a0B);  b0B = fmaf(p01, whi1, b0B);
                a1B = fmaf(p11, wlo1, a1B);  b1B = fmaf(p11, whi1, b1B);
            }
            const float i10_0 = tanh_fast(a0A + a0B);
            const float i11_0 = tanh_fast(b0A + b0B);
            const float i10_1 = tanh_fast(a1A + a1B);
            const float i11_1 = tanh_fast(b1A + b1B);

            // ---- emit pair 0 ----
            {
                const size_t pA = (size_t)Up0;
                __builtin_nontemporal_store(i10_0, &out_i1[pA * 128 + l]);
                __builtin_nontemporal_store(i11_0, &out_i1[pA * 128 + 64 + l]);
                agg1a += i10_0;
                agg1b += i11_0;
                float ix0 = (qiv[0] + lo_bf(Uvq0.z) + Ud0x) * i11_0;
                float ix1 = (qiv[1] + hi_bf(Uvq0.z) + Ud0y) * i11_0;
                float ix2 = (qiv[2] + lo_bf(Uvq0.w) + Ud0z) * i11_0;
                __builtin_nontemporal_store(ix0, &out_ix[(pA * 3 + 0) * 64 + l]);
                __builtin_nontemporal_store(ix1, &out_ix[(pA * 3 + 1) * 64 + l]);
                __builtin_nontemporal_store(ix2, &out_ix[(pA * 3 + 2) * 64 + l]);
                agg30 += ix0; agg31 += ix1; agg32 += ix2;
            }
            // ---- emit pair 1 (wave-uniform validity) ----
            if (it + 1 < end) {
                const size_t pA = (size_t)Up1;
                __builtin_nontemporal_store(i10_1, &out_i1[pA * 128 + l]);
                __builtin_nontemporal_store(i11_1, &out_i1[pA * 128 + 64 + l]);
                agg1a += i10_1;
                agg1b += i11_1;
                float ix0 = (qiv[0] + lo_bf(Uvq1.z) + Ud1x) * i11_1;
                float ix1 = (qiv[1] + hi_bf(Uvq1.z) + Ud1y) * i11_1;
                float ix2 = (qiv[2] + lo_bf(Uvq1.w) + Ud1z) * i11_1;
                __builtin_nontemporal_store(ix0, &out_ix[(pA * 3 + 0) * 64 + l]);
                __builtin_nontemporal_store(ix1, &out_ix[(pA * 3 + 1) * 64 + l]);
                __builtin_nontemporal_store(ix2, &out_ix[(pA * 3 + 2) * 64 + l]);
                agg30 += ix0; agg31 += ix1; agg32 += ix2;
            }

            // ---- rotate: U <- M, M <- R (extract fields), issue new M vq ----
            Up0 = Mp0; Up1 = Mp1;
            Ud0x = Md0x; Ud0y = Md0y; Ud0z = Md0z;
            Ud1x = Md1x; Ud1y = Md1y; Ud1z = Md1z;
            Ubs0 = Mbs0; Ubs1 = Mbs1;
            Uvq0 = Mvq0; Uvq1 = Mvq1;

            Mp0 = __builtin_bit_cast(int, ra.x);
            Mj0 = __builtin_bit_cast(int, ra.y);
            Md0x = ra.z; Md0y = ra.w; Md0z = rz0; Mbs0 = rb0;
            Mp1 = __builtin_bit_cast(int, rb.x);
            Mj1 = __builtin_bit_cast(int, rb.y);
            Md1x = rb.z; Md1y = rb.w; Md1z = rz1; Mbs1 = rb1;
            Mvq0 = *(const uint4*)&vq[(size_t)Mj0 * 512 + 8 * l];
            Mvq1 = *(const uint4*)&vq[(size_t)Mj1 * 512 + 8 * l];
        }
    }

    p1_agg[(size_t)n * 128 + l]      = agg1a;
    p1_agg[(size_t)n * 128 + 64 + l] = agg1b;
    p3_agg[(size_t)n * 192 + l]       = agg30;
    p3_agg[(size_t)n * 192 + 64 + l]  = agg31;
    p3_agg[(size_t)n * 192 + 128 + l] = agg32;
}

// ---------------------------------------------------------------------------
// K3: per-atom tail.
// ---------------------------------------------------------------------------
extern "C" __global__ __launch_bounds__(256, 4)
void k3_atoms(const float* __restrict__ p1_agg,
              const float* __restrict__ p3_agg,
              const float* __restrict__ W_pp,
              const float* __restrict__ W_ppx,
              const float* __restrict__ wi_dot,
              const float* __restrict__ wj_dot,
              const float* __restrict__ W_pp1,
              const float* __restrict__ b_pp1,
              float* __restrict__ out_p1,
              float* __restrict__ out_p3,
              float* __restrict__ out_dot)
{
    __shared__ float s1[4][128];
    __shared__ float s3[4][192];
    __shared__ float sPm[4][192];
    __shared__ float sCat[4][128];

    const int w = threadIdx.x >> 6;
    const int l = threadIdx.x & 63;
    const int n = blockIdx.x * 4 + w;    // grid = 6250 exactly

    s1[w][l]      = p1_agg[(size_t)n * 128 + l];
    s1[w][64 + l] = p1_agg[(size_t)n * 128 + 64 + l];
    #pragma unroll
    for (int x = 0; x < 3; ++x)
        s3[w][x * 64 + l] = p3_agg[(size_t)n * 192 + x * 64 + l];
    __syncthreads();

    float pn = 0.0f;
    #pragma unroll 4
    for (int k = 0; k < 128; ++k)
        pn = fmaf(s1[w][k], W_pp[k * 64 + l], pn);
    pn = tanh_fast(pn);

    float pm[3];
    #pragma unroll
    for (int x = 0; x < 3; ++x) {
        float s = 0.0f;
        #pragma unroll 4
        for (int c = 0; c < 64; ++c)
            s = fmaf(s3[w][x * 64 + c], W_ppx[c * 64 + l], s);
        pm[x] = s;
        sPm[w][x * 64 + l] = s;
    }
    __syncthreads();

    float dot = 0.0f;
    #pragma unroll
    for (int x = 0; x < 3; ++x) {
        float vi = 0.0f, vj = 0.0f;
        #pragma unroll 4
        for (int c = 0; c < 64; ++c) {
            float a = sPm[w][x * 64 + c];
            vi = fmaf(a, wi_dot[c * 64 + l], vi);
            vj = fmaf(a, wj_dot[c * 64 + l], vj);
        }
        dot = fmaf(vi, vj, dot);
    }

    sCat[w][l]      = pn;
    sCat[w][64 + l] = dot;
    __syncthreads();

    float u1 = b_pp1[l];
    float u2 = b_pp1[64 + l];
    #pragma unroll 4
    for (int k = 0; k < 128; ++k) {
        float ck = sCat[w][k];
        u1 = fmaf(ck, W_pp1[k * 128 + l], u1);
        u2 = fmaf(ck, W_pp1[k * 128 + 64 + l], u2);
    }
    float p1o = tanh_fast(u1);
    float s3v = tanh_fast(u2);

    out_p1[(size_t)n * 64 + l]  = p1o;
    out_dot[(size_t)n * 64 + l] = dot;
    #pragma unroll
    for (int x = 0; x < 3; ++x)
        out_p3[((size_t)n * 3 + x) * 64 + l] = pm[x] * s3v;
}

// ---------------------------------------------------------------------------
extern "C" void kernel_launch(void* const* d_in, const int* in_sizes, int n_in,
                              void* d_out, int out_size, void* d_ws, size_t ws_size,
                              hipStream_t stream)
{
    const int*   ind2   = (const int*)d_in[0];
    const float* p1     = (const float*)d_in[1];
    const float* p3     = (const float*)d_in[2];
    const float* d3     = (const float*)d_in[3];
    const float* basis  = (const float*)d_in[4];
    const float* W_pi   = (const float*)d_in[5];
    const float* b_pi   = (const float*)d_in[6];
    const float* W_ii   = (const float*)d_in[7];
    const float* W_pp   = (const float*)d_in[8];
    const float* wi_pix = (const float*)d_in[9];
    const float* wj_pix = (const float*)d_in[10];
    const float* W_ppx  = (const float*)d_in[11];
    const float* wi_dot = (const float*)d_in[12];
    const float* wj_dot = (const float*)d_in[13];
    const float* W_pp1  = (const float*)d_in[14];
    const float* b_pp1  = (const float*)d_in[15];

    float* out     = (float*)d_out;
    float* out_p1  = out;                      // 25000*64
    float* out_p3  = out + 1600000;            // 25000*192
    float* out_dot = out + 6400000;            // 25000*64
    float* out_i1  = out + 8000000;            // 500000*128
    float* out_ix  = out + 72000000;           // 500000*192

    // workspace (~130MB of the ~2.7GB ws)
    float*          u      = (float*)d_ws;                       // 6,400,000 f32
    unsigned short* vq     = (unsigned short*)(u + 6400000);     // 12,800,000 us
    unsigned short* qi_bf  = vq + 12800000;                      // 6,400,000 us
    float*          p1_agg = (float*)(qi_bf + 6400000);          // 3,200,000 f32
    float*          p3_agg = p1_agg + 3200000;                   // 4,800,000 f32
    float*          prec   = p3_agg + 4800000;                   // 8,000,000 f32 (500k × 64B records)
    int*            cnt      = (int*)(prec + 8000000 + 32);      // 25,000 (+2 recs overrun pad)
    int*            rowstart = cnt + 25000;                      // 25,001
    int*            cursor   = rowstart + 25001;                 // 25,000

    hipMemsetAsync(cnt, 0, (size_t)75001 * sizeof(int), stream);

    dim3 blk(256);
    k0_uv    <<<dim3(1563), blk, 0, stream>>>(p1, W_pi, b_pi, u, vq);
    k0_q     <<<dim3(6250), blk, 0, stream>>>(p3, wi_pix, wj_pix, ind2, cnt,
                                              qi_bf, vq);
    csr_scan <<<dim3(1), dim3(1024), 0, stream>>>(cnt, rowstart);
    k_scatter<<<dim3(1954), blk, 0, stream>>>(ind2, d3, basis, rowstart, cursor, prec);
    k_pair   <<<dim3(6250), blk, 0, stream>>>(prec, W_ii, u, vq,
                                              qi_bf, rowstart,
                                              out_i1, out_ix, p1_agg, p3_agg);
    k3_atoms <<<dim3(6250), blk, 0, stream>>>(p1_agg, p3_agg, W_pp, W_ppx,
                                              wi_dot, wj_dot, W_pp1, b_pp1,
                                              out_p1, out_p3, out_dot);
}

// Round 11
// 583.155 us; speedup vs baseline: 1.2906x; 1.2906x over previous
//
#include <hip/hip_runtime.h>

#define NP 500000
#define NA 25000

typedef float v2f __attribute__((ext_vector_type(2)));

// native-rcp tanh: exp + v_rcp (~1ulp) instead of IEEE divide expansion
__device__ __forceinline__ float tanh_fast(float x) {
    float e = __expf(2.0f * x);
    return 1.0f - __fdividef(2.0f, e + 1.0f);
}

// readlane with float bitcast (__builtin_amdgcn_readlane is (int,int);
// passing float value-converts = truncates — the R2/R3 bug).
__device__ __forceinline__ float readlane_f(float v, int lane) {
    int iv = __builtin_bit_cast(int, v);
    int r = __builtin_amdgcn_readlane(iv, lane);
    return __builtin_bit_cast(float, r);
}

// Sum over each consecutive 8-lane group, all in VALU (DPP), no LDS.
__device__ __forceinline__ float dpp8_reduce(float s) {
    int x;
    x = __builtin_amdgcn_update_dpp(0, __builtin_bit_cast(int, s), 0xB1, 0xF, 0xF, true);
    s += __builtin_bit_cast(float, x);
    x = __builtin_amdgcn_update_dpp(0, __builtin_bit_cast(int, s), 0x4E, 0xF, 0xF, true);
    s += __builtin_bit_cast(float, x);
    x = __builtin_amdgcn_update_dpp(0, __builtin_bit_cast(int, s), 0x141, 0xF, 0xF, true);
    s += __builtin_bit_cast(float, x);
    return s;
}

__device__ __forceinline__ unsigned short f2bf(float x) {
    union { float f; unsigned int u; } c; c.f = x;
    unsigned int r = c.u + 0x7FFFu + ((c.u >> 16) & 1u);
    return (unsigned short)(r >> 16);
}
__device__ __forceinline__ float bf2f(unsigned short h) {
    union { unsigned int u; float f; } c; c.u = ((unsigned int)h) << 16;
    return c.f;
}
__device__ __forceinline__ unsigned int pack2bf(float a, float b) {
    return (unsigned int)f2bf(a) | ((unsigned int)f2bf(b) << 16);
}
__device__ __forceinline__ float lo_bf(unsigned int x) { return bf2f((unsigned short)(x & 0xffffu)); }
__device__ __forceinline__ float hi_bf(unsigned int x) { return bf2f((unsigned short)(x >> 16)); }
__device__ __forceinline__ float lo_bf_f(unsigned int x) {
    return __builtin_bit_cast(float, x << 16);
}
__device__ __forceinline__ float hi_bf_f(unsigned int x) {
    return __builtin_bit_cast(float, x & 0xffff0000u);
}
// unpack (lo,hi) bf16 pair into a packed float2 operand
__device__ __forceinline__ v2f w2_bf(unsigned int x) {
    v2f r;
    r.x = lo_bf_f(x);
    r.y = hi_bf_f(x);
    return r;
}

// ---------------------------------------------------------------------------
// K0a: 16 atoms/block.  u = p1 @ W_pi[0:64,:] + b_pi  (f32 [atom][col])
//      v = p1 @ W_pi[64:128,:] -> vq[atom][l*8 + 0..3]  (bf16, col = 64q+l)
// ---------------------------------------------------------------------------
extern "C" __global__ __launch_bounds__(256, 2)
void k0_uv(const float* __restrict__ p1,
           const float* __restrict__ W_pi,
           const float* __restrict__ b_pi,
           float* __restrict__ u,
           unsigned short* __restrict__ vq)
{
    __shared__ float sW[32 * 256];     // 32 KB
    __shared__ float sp1[16 * 64];     //  4 KB

    const int t = threadIdx.x;
    const int wv = t >> 6;
    const int l = t & 63;
    const int atom0 = blockIdx.x * 16;

    #pragma unroll
    for (int f = 0; f < 4; ++f) {
        int idx = f * 256 + t;
        int at = atom0 + (idx >> 6);
        int atc = at < NA ? at : NA - 1;
        sp1[idx] = p1[(size_t)atc * 64 + (idx & 63)];
    }

    float accu[4][4] = {{0}}, accv[4][4] = {{0}};

    #pragma unroll
    for (int s = 0; s < 4; ++s) {
        __syncthreads();
        {
            const float4* src = (const float4*)(W_pi + s * 32 * 256);
            float4* dst = (float4*)sW;
            #pragma unroll
            for (int f = 0; f < 8; ++f) dst[f * 256 + t] = src[f * 256 + t];
        }
        __syncthreads();
        const int kbase = (s & 1) * 32;
        #pragma unroll 2
        for (int k = 0; k < 32; ++k) {
            float wq[4];
            #pragma unroll
            for (int q = 0; q < 4; ++q) wq[q] = sW[k * 256 + 64 * q + l];
            #pragma unroll
            for (int a = 0; a < 4; ++a) {
                float pv = sp1[(wv * 4 + a) * 64 + kbase + k];
                #pragma unroll
                for (int q = 0; q < 4; ++q) {
                    if (s < 2) accu[a][q] = fmaf(pv, wq[q], accu[a][q]);
                    else       accv[a][q] = fmaf(pv, wq[q], accv[a][q]);
                }
            }
        }
    }

    #pragma unroll
    for (int a = 0; a < 4; ++a) {
        const int at = atom0 + wv * 4 + a;
        if (at < NA) {
            #pragma unroll
            for (int q = 0; q < 4; ++q)
                u[(size_t)at * 256 + 64 * q + l] = accu[a][q] + b_pi[64 * q + l];
            uint2 vv;
            vv.x = pack2bf(accv[a][0], accv[a][1]);
            vv.y = pack2bf(accv[a][2], accv[a][3]);
            *(uint2*)&vq[(size_t)at * 512 + 8 * l] = vv;
        }
    }
}

// ---------------------------------------------------------------------------
// K0b (+fused pair count): qi = p3 @ wi_pix -> qi_bf[atom][4l+x];
//                          qj = p3 @ wj_pix -> vq[atom][8l+4..6]
// ---------------------------------------------------------------------------
extern "C" __global__ __launch_bounds__(256, 4)
void k0_q(const float* __restrict__ p3,
          const float* __restrict__ wi_pix,
          const float* __restrict__ wj_pix,
          const int* __restrict__ ind2,
          int* __restrict__ cnt,
          unsigned short* __restrict__ qi_bf,
          unsigned short* __restrict__ vq)
{
    __shared__ float sWi[64 * 64];
    __shared__ float sWj[64 * 64];

    const int t = threadIdx.x;

    // fused k_count: first 1954 blocks also count pairs
    {
        int gp = blockIdx.x * 256 + t;
        if (gp < NP) atomicAdd(&cnt[ind2[2 * gp]], 1);
    }

    {
        const float4* si = (const float4*)wi_pix;
        const float4* sj = (const float4*)wj_pix;
        float4* di = (float4*)sWi;
        float4* dj = (float4*)sWj;
        #pragma unroll
        for (int f = 0; f < 4; ++f) { di[f * 256 + t] = si[f * 256 + t]; dj[f * 256 + t] = sj[f * 256 + t]; }
    }
    __syncthreads();

    const int w = t >> 6;
    const int l = t & 63;
    const int atom = blockIdx.x * 4 + w;     // grid 6250 -> < 25000

    float val0 = p3[((size_t)atom * 3 + 0) * 64 + l];
    float val1 = p3[((size_t)atom * 3 + 1) * 64 + l];
    float val2 = p3[((size_t)atom * 3 + 2) * 64 + l];

    float ai[3] = {0, 0, 0}, aj[3] = {0, 0, 0};
    #pragma unroll 8
    for (int k = 0; k < 64; ++k) {
        float a0 = readlane_f(val0, k);
        float a1 = readlane_f(val1, k);
        float a2 = readlane_f(val2, k);
        float wi = sWi[k * 64 + l];
        float wj = sWj[k * 64 + l];
        ai[0] = fmaf(a0, wi, ai[0]); aj[0] = fmaf(a0, wj, aj[0]);
        ai[1] = fmaf(a1, wi, ai[1]); aj[1] = fmaf(a1, wj, aj[1]);
        ai[2] = fmaf(a2, wi, ai[2]); aj[2] = fmaf(a2, wj, aj[2]);
    }
    uint2 iu, ju;
    iu.x = pack2bf(ai[0], ai[1]); iu.y = pack2bf(ai[2], 0.0f);
    ju.x = pack2bf(aj[0], aj[1]); ju.y = pack2bf(aj[2], 0.0f);
    *(uint2*)&qi_bf[(size_t)atom * 256 + 4 * l] = iu;
    *(uint2*)&vq[(size_t)atom * 512 + 8 * l + 4] = ju;
}

// ---------------------------------------------------------------------------
// CSR build
// ---------------------------------------------------------------------------
extern "C" __global__ __launch_bounds__(1024)
void csr_scan(const int* __restrict__ cnt, int* __restrict__ rowstart)
{
    __shared__ int ssum[1024];
    const int t = threadIdx.x;
    const int base = t * 25;

    int s = 0;
    #pragma unroll 5
    for (int i = 0; i < 25; ++i) {
        int idx = base + i;
        s += (idx < NA) ? cnt[idx] : 0;
    }
    ssum[t] = s;
    __syncthreads();
    for (int off = 1; off < 1024; off <<= 1) {
        int vv = (t >= off) ? ssum[t - off] : 0;
        __syncthreads();
        ssum[t] += vv;
        __syncthreads();
    }
    int run = (t > 0) ? ssum[t - 1] : 0;
    for (int i = 0; i < 25; ++i) {
        int idx = base + i;
        if (idx <= NA) rowstart[idx] = run;
        run += (idx < NA) ? cnt[idx] : 0;
    }
}

extern "C" __global__ void k_scatter(const int* __restrict__ ind2,
                                     const int* __restrict__ rowstart,
                                     int* __restrict__ cursor,
                                     int2* __restrict__ plist2)
{
    int p = blockIdx.x * 256 + threadIdx.x;
    if (p < NP) {
        int ii = ind2[2 * p];
        int jj = ind2[2 * p + 1];
        int pos = atomicAdd(&cursor[ii], 1);
        plist2[rowstart[ii] + pos] = make_int2(p, jj);
    }
}

// ---------------------------------------------------------------------------
// K_pair: wave per atom; TWO pairs per iteration (independent chains),
// prefetch 1 iteration (=2 pairs) ahead. One 16B gather per pair.
// W_ii matmul uses packed float2 accumulators (v_pk_fma_f32).
// ---------------------------------------------------------------------------
extern "C" __global__ __launch_bounds__(256, 4)
void k_pair(const float* __restrict__ d3,
            const float* __restrict__ basis,
            const float* __restrict__ W_ii,
            const float* __restrict__ u,
            const unsigned short* __restrict__ vq,
            const unsigned short* __restrict__ qi_bf,
            const int* __restrict__ rowstart,
            const int2* __restrict__ plist2,
            float* __restrict__ out_i1,
            float* __restrict__ out_ix,
            float* __restrict__ p1_agg,
            float* __restrict__ p3_agg)
{
    const int t = threadIdx.x;
    const int w = t >> 6;
    const int l = t & 63;
    const int n = blockIdx.x * 4 + w;        // grid 6250*4 = 25000 exactly

    // W_ii columns l (lo) and 64+l (hi) packed as bf16 pairs: 32 VGPRs
    unsigned int wAB[32];
    #pragma unroll
    for (int c = 0; c < 32; ++c)
        wAB[c] = pack2bf(W_ii[c * 128 + l], W_ii[c * 128 + 64 + l]);

    float uu[4];
    #pragma unroll
    for (int q = 0; q < 4; ++q) uu[q] = u[(size_t)n * 256 + 64 * q + l];
    float qiv[3];
    {
        uint2 iu = *(const uint2*)&qi_bf[(size_t)n * 256 + 4 * l];
        qiv[0] = lo_bf(iu.x); qiv[1] = hi_bf(iu.x); qiv[2] = lo_bf(iu.y);
    }

    const int start = rowstart[n];
    const int end   = rowstart[n + 1];

    float agg1a = 0.0f, agg1b = 0.0f;
    float agg30 = 0.0f, agg31 = 0.0f, agg32 = 0.0f;

    if (start < end) {
        const int last = end - 1;

        // slot S0/S1 = current two pairs; T0/T1 = next two (in flight)
        int2 pj0, pj1;
        uint4 vq0, vq1;
        float bs0, bs1;
        float d0x, d0y, d0z, d1x, d1y, d1z;

        {
            int iA = start;
            int iB = (start + 1 <= last) ? start + 1 : last;
            pj0 = plist2[iA];
            pj1 = plist2[iB];
            vq0 = *(const uint4*)&vq[(size_t)pj0.y * 512 + 8 * l];
            vq1 = *(const uint4*)&vq[(size_t)pj1.y * 512 + 8 * l];
            bs0 = basis[(size_t)pj0.x * 8 + (l & 7)];
            bs1 = basis[(size_t)pj1.x * 8 + (l & 7)];
            d0x = d3[3 * (size_t)pj0.x + 0]; d0y = d3[3 * (size_t)pj0.x + 1]; d0z = d3[3 * (size_t)pj0.x + 2];
            d1x = d3[3 * (size_t)pj1.x + 0]; d1y = d3[3 * (size_t)pj1.x + 1]; d1z = d3[3 * (size_t)pj1.x + 2];
        }

        for (int it = start; it < end; it += 2) {
            // ---- prefetch next two pairs ----
            int iC = (it + 2 <= last) ? it + 2 : last;
            int iD = (it + 3 <= last) ? it + 3 : last;
            int2 pjT0 = plist2[iC];
            int2 pjT1 = plist2[iD];
            uint4 vqT0 = *(const uint4*)&vq[(size_t)pjT0.y * 512 + 8 * l];
            uint4 vqT1 = *(const uint4*)&vq[(size_t)pjT1.y * 512 + 8 * l];
            float bsT0 = basis[(size_t)pjT0.x * 8 + (l & 7)];
            float bsT1 = basis[(size_t)pjT1.x * 8 + (l & 7)];
            float dT0x = d3[3 * (size_t)pjT0.x + 0];
            float dT0y = d3[3 * (size_t)pjT0.x + 1];
            float dT0z = d3[3 * (size_t)pjT0.x + 2];
            float dT1x = d3[3 * (size_t)pjT1.x + 0];
            float dT1y = d3[3 * (size_t)pjT1.x + 1];
            float dT1z = d3[3 * (size_t)pjT1.x + 2];

            // ---- compute pair 0 and pair 1 with interleaved chains ----
            float h00 = tanh_fast(uu[0] + lo_bf(vq0.x));
            float h10 = tanh_fast(uu[0] + lo_bf(vq1.x));
            float h01 = tanh_fast(uu[1] + hi_bf(vq0.x));
            float h11 = tanh_fast(uu[1] + hi_bf(vq1.x));
            float h02 = tanh_fast(uu[2] + lo_bf(vq0.y));
            float h12 = tanh_fast(uu[2] + lo_bf(vq1.y));
            float h03 = tanh_fast(uu[3] + hi_bf(vq0.y));
            float h13 = tanh_fast(uu[3] + hi_bf(vq1.y));

            float pre0[4], pre1[4];
            pre0[0] = dpp8_reduce(h00 * bs0);
            pre1[0] = dpp8_reduce(h10 * bs1);
            pre0[1] = dpp8_reduce(h01 * bs0);
            pre1[1] = dpp8_reduce(h11 * bs1);
            pre0[2] = dpp8_reduce(h02 * bs0);
            pre1[2] = dpp8_reduce(h12 * bs1);
            pre0[3] = dpp8_reduce(h03 * bs0);
            pre1[3] = dpp8_reduce(h13 * bs1);

            // packed (lo=col l, hi=col 64+l) accumulators -> v_pk_fma_f32
            v2f acc0A = {0.0f, 0.0f}, acc0B = {0.0f, 0.0f};
            v2f acc1A = {0.0f, 0.0f}, acc1B = {0.0f, 0.0f};
            #pragma unroll
            for (int c = 0; c < 32; c += 2) {
                float p00 = readlane_f(pre0[c >> 3], 8 * (c & 7));
                float p10 = readlane_f(pre1[c >> 3], 8 * (c & 7));
                float p01 = readlane_f(pre0[(c + 1) >> 3], 8 * ((c + 1) & 7));
                float p11 = readlane_f(pre1[(c + 1) >> 3], 8 * ((c + 1) & 7));
                v2f w0 = w2_bf(wAB[c]);
                v2f w1 = w2_bf(wAB[c + 1]);
                v2f s00 = {p00, p00}, s10 = {p10, p10};
                v2f s01 = {p01, p01}, s11 = {p11, p11};
                acc0A += s00 * w0;
                acc1A += s10 * w0;
                acc0B += s01 * w1;
                acc1B += s11 * w1;
            }
            const float i10_0 = tanh_fast(acc0A.x + acc0B.x);
            const float i11_0 = tanh_fast(acc0A.y + acc0B.y);
            const float i10_1 = tanh_fast(acc1A.x + acc1B.x);
            const float i11_1 = tanh_fast(acc1A.y + acc1B.y);

            // ---- emit pair 0 (always valid) ----
            {
                const size_t pA = (size_t)pj0.x;
                __builtin_nontemporal_store(i10_0, &out_i1[pA * 128 + l]);
                __builtin_nontemporal_store(i11_0, &out_i1[pA * 128 + 64 + l]);
                agg1a += i10_0;
                agg1b += i11_0;
                float ix0 = (qiv[0] + lo_bf(vq0.z) + d0x) * i11_0;
                float ix1 = (qiv[1] + hi_bf(vq0.z) + d0y) * i11_0;
                float ix2 = (qiv[2] + lo_bf(vq0.w) + d0z) * i11_0;
                __builtin_nontemporal_store(ix0, &out_ix[(pA * 3 + 0) * 64 + l]);
                __builtin_nontemporal_store(ix1, &out_ix[(pA * 3 + 1) * 64 + l]);
                __builtin_nontemporal_store(ix2, &out_ix[(pA * 3 + 2) * 64 + l]);
                agg30 += ix0; agg31 += ix1; agg32 += ix2;
            }
            // ---- emit pair 1 (wave-uniform validity) ----
            if (it + 1 < end) {
                const size_t pA = (size_t)pj1.x;
                __builtin_nontemporal_store(i10_1, &out_i1[pA * 128 + l]);
                __builtin_nontemporal_store(i11_1, &out_i1[pA * 128 + 64 + l]);
                agg1a += i10_1;
                agg1b += i11_1;
                float ix0 = (qiv[0] + lo_bf(vq1.z) + d1x) * i11_1;
                float ix1 = (qiv[1] + hi_bf(vq1.z) + d1y) * i11_1;
                float ix2 = (qiv[2] + lo_bf(vq1.w) + d1z) * i11_1;
                __builtin_nontemporal_store(ix0, &out_ix[(pA * 3 + 0) * 64 + l]);
                __builtin_nontemporal_store(ix1, &out_ix[(pA * 3 + 1) * 64 + l]);
                __builtin_nontemporal_store(ix2, &out_ix[(pA * 3 + 2) * 64 + l]);
                agg30 += ix0; agg31 += ix1; agg32 += ix2;
            }

            // rotate
            pj0 = pjT0; vq0 = vqT0; bs0 = bsT0; d0x = dT0x; d0y = dT0y; d0z = dT0z;
            pj1 = pjT1; vq1 = vqT1; bs1 = bsT1; d1x = dT1x; d1y = dT1y; d1z = dT1z;
        }
    }

    p1_agg[(size_t)n * 128 + l]      = agg1a;
    p1_agg[(size_t)n * 128 + 64 + l] = agg1b;
    p3_agg[(size_t)n * 192 + l]       = agg30;
    p3_agg[(size_t)n * 192 + 64 + l]  = agg31;
    p3_agg[(size_t)n * 192 + 128 + l] = agg32;
}

// ---------------------------------------------------------------------------
// K3: per-atom tail.
// ---------------------------------------------------------------------------
extern "C" __global__ __launch_bounds__(256, 4)
void k3_atoms(const float* __restrict__ p1_agg,
              const float* __restrict__ p3_agg,
              const float* __restrict__ W_pp,
              const float* __restrict__ W_ppx,
              const float* __restrict__ wi_dot,
              const float* __restrict__ wj_dot,
              const float* __restrict__ W_pp1,
              const float* __restrict__ b_pp1,
              float* __restrict__ out_p1,
              float* __restrict__ out_p3,
              float* __restrict__ out_dot)
{
    __shared__ float s1[4][128];
    __shared__ float s3[4][192];
    __shared__ float sPm[4][192];
    __shared__ float sCat[4][128];

    const int w = threadIdx.x >> 6;
    const int l = threadIdx.x & 63;
    const int n = blockIdx.x * 4 + w;    // grid = 6250 exactly

    s1[w][l]      = p1_agg[(size_t)n * 128 + l];
    s1[w][64 + l] = p1_agg[(size_t)n * 128 + 64 + l];
    #pragma unroll
    for (int x = 0; x < 3; ++x)
        s3[w][x * 64 + l] = p3_agg[(size_t)n * 192 + x * 64 + l];
    __syncthreads();

    float pn = 0.0f;
    #pragma unroll 4
    for (int k = 0; k < 128; ++k)
        pn = fmaf(s1[w][k], W_pp[k * 64 + l], pn);
    pn = tanh_fast(pn);

    float pm[3];
    #pragma unroll
    for (int x = 0; x < 3; ++x) {
        float s = 0.0f;
        #pragma unroll 4
        for (int c = 0; c < 64; ++c)
            s = fmaf(s3[w][x * 64 + c], W_ppx[c * 64 + l], s);
        pm[x] = s;
        sPm[w][x * 64 + l] = s;
    }
    __syncthreads();

    float dot = 0.0f;
    #pragma unroll
    for (int x = 0; x < 3; ++x) {
        float vi = 0.0f, vj = 0.0f;
        #pragma unroll 4
        for (int c = 0; c < 64; ++c) {
            float a = sPm[w][x * 64 + c];
            vi = fmaf(a, wi_dot[c * 64 + l], vi);
            vj = fmaf(a, wj_dot[c * 64 + l], vj);
        }
        dot = fmaf(vi, vj, dot);
    }

    sCat[w][l]      = pn;
    sCat[w][64 + l] = dot;
    __syncthreads();

    float u1 = b_pp1[l];
    float u2 = b_pp1[64 + l];
    #pragma unroll 4
    for (int k = 0; k < 128; ++k) {
        float ck = sCat[w][k];
        u1 = fmaf(ck, W_pp1[k * 128 + l], u1);
        u2 = fmaf(ck, W_pp1[k * 128 + 64 + l], u2);
    }
    float p1o = tanh_fast(u1);
    float s3v = tanh_fast(u2);

    out_p1[(size_t)n * 64 + l]  = p1o;
    out_dot[(size_t)n * 64 + l] = dot;
    #pragma unroll
    for (int x = 0; x < 3; ++x)
        out_p3[((size_t)n * 3 + x) * 64 + l] = pm[x] * s3v;
}

// ---------------------------------------------------------------------------
extern "C" void kernel_launch(void* const* d_in, const int* in_sizes, int n_in,
                              void* d_out, int out_size, void* d_ws, size_t ws_size,
                              hipStream_t stream)
{
    const int*   ind2   = (const int*)d_in[0];
    const float* p1     = (const float*)d_in[1];
    const float* p3     = (const float*)d_in[2];
    const float* d3     = (const float*)d_in[3];
    const float* basis  = (const float*)d_in[4];
    const float* W_pi   = (const float*)d_in[5];
    const float* b_pi   = (const float*)d_in[6];
    const float* W_ii   = (const float*)d_in[7];
    const float* W_pp   = (const float*)d_in[8];
    const float* wi_pix = (const float*)d_in[9];
    const float* wj_pix = (const float*)d_in[10];
    const float* W_ppx  = (const float*)d_in[11];
    const float* wi_dot = (const float*)d_in[12];
    const float* wj_dot = (const float*)d_in[13];
    const float* W_pp1  = (const float*)d_in[14];
    const float* b_pp1  = (const float*)d_in[15];

    float* out     = (float*)d_out;
    float* out_p1  = out;                      // 25000*64
    float* out_p3  = out + 1600000;            // 25000*192
    float* out_dot = out + 6400000;            // 25000*64
    float* out_i1  = out + 8000000;            // 500000*128
    float* out_ix  = out + 72000000;           // 500000*192

    // workspace (~95MB of the ~2.7GB ws)
    float*          u      = (float*)d_ws;                       // 6,400,000 f32
    unsigned short* vq     = (unsigned short*)(u + 6400000);     // 12,800,000 us (v|qj interleaved)
    unsigned short* qi_bf  = vq + 12800000;                      // 6,400,000 us
    float*          p1_agg = (float*)(qi_bf + 6400000);          // 3,200,000 f32
    float*          p3_agg = p1_agg + 3200000;                   // 4,800,000 f32
    int2*           plist2 = (int2*)(p3_agg + 4800000);          // 500,000 int2 (8B-aligned)
    int*            cnt      = (int*)(plist2 + 500000);          // 25,000
    int*            rowstart = cnt + 25000;                      // 25,001
    int*            cursor   = rowstart + 25001;                 // 25,000

    hipMemsetAsync(cnt, 0, (size_t)75001 * sizeof(int), stream);

    dim3 blk(256);
    k0_uv    <<<dim3(1563), blk, 0, stream>>>(p1, W_pi, b_pi, u, vq);
    k0_q     <<<dim3(6250), blk, 0, stream>>>(p3, wi_pix, wj_pix, ind2, cnt,
                                              qi_bf, vq);
    csr_scan <<<dim3(1), dim3(1024), 0, stream>>>(cnt, rowstart);
    k_scatter<<<dim3(1954), blk, 0, stream>>>(ind2, rowstart, cursor, plist2);
    k_pair   <<<dim3(6250), blk, 0, stream>>>(d3, basis, W_ii, u, vq,
                                              qi_bf, rowstart, plist2,
                                              out_i1, out_ix, p1_agg, p3_agg);
    k3_atoms <<<dim3(6250), blk, 0, stream>>>(p1_agg, p3_agg, W_pp, W_ppx,
                                              wi_dot, wj_dot, W_pp1, b_pp1,
                                              out_p1, out_p3, out_dot);
}

// Round 12
// 566.125 us; speedup vs baseline: 1.3295x; 1.0301x over previous
//
#include <hip/hip_runtime.h>

#define NP 500000
#define NA 25000

typedef float v2f __attribute__((ext_vector_type(2)));

// native-rcp tanh: exp + v_rcp (~1ulp) instead of IEEE divide expansion
__device__ __forceinline__ float tanh_fast(float x) {
    float e = __expf(2.0f * x);
    return 1.0f - __fdividef(2.0f, e + 1.0f);
}

// readlane with float bitcast (__builtin_amdgcn_readlane is (int,int);
// passing float value-converts = truncates — the R2/R3 bug).
__device__ __forceinline__ float readlane_f(float v, int lane) {
    int iv = __builtin_bit_cast(int, v);
    int r = __builtin_amdgcn_readlane(iv, lane);
    return __builtin_bit_cast(float, r);
}

// add value from lane^1 (quad_perm(1,0,3,2) = 0xB1), pure VALU
__device__ __forceinline__ float dpp_xor1_add(float s) {
    int x = __builtin_amdgcn_update_dpp(0, __builtin_bit_cast(int, s), 0xB1, 0xF, 0xF, true);
    return s + __builtin_bit_cast(float, x);
}

__device__ __forceinline__ unsigned short f2bf(float x) {
    union { float f; unsigned int u; } c; c.f = x;
    unsigned int r = c.u + 0x7FFFu + ((c.u >> 16) & 1u);
    return (unsigned short)(r >> 16);
}
__device__ __forceinline__ float bf2f(unsigned short h) {
    union { unsigned int u; float f; } c; c.u = ((unsigned int)h) << 16;
    return c.f;
}
__device__ __forceinline__ unsigned int pack2bf(float a, float b) {
    return (unsigned int)f2bf(a) | ((unsigned int)f2bf(b) << 16);
}
__device__ __forceinline__ float lo_bf(unsigned int x) { return bf2f((unsigned short)(x & 0xffffu)); }
__device__ __forceinline__ float hi_bf(unsigned int x) { return bf2f((unsigned short)(x >> 16)); }
__device__ __forceinline__ float lo_bf_f(unsigned int x) {
    return __builtin_bit_cast(float, x << 16);
}
__device__ __forceinline__ float hi_bf_f(unsigned int x) {
    return __builtin_bit_cast(float, x & 0xffff0000u);
}
// unpack a (lo,hi) bf16 pair into a packed float2 operand
__device__ __forceinline__ v2f w2_bf(unsigned int x) {
    v2f r;
    r.x = lo_bf_f(x);
    r.y = hi_bf_f(x);
    return r;
}

// ---------------------------------------------------------------------------
// K0a: 16 atoms/block.  Lane l computes cols {4l+q} (q=0..3):
//   u[atom][4l+q]  (f32, float4 store)
//   v -> vq[atom][8l+0..3] (bf16), col meaning = 4l+q
// ---------------------------------------------------------------------------
extern "C" __global__ __launch_bounds__(256, 2)
void k0_uv(const float* __restrict__ p1,
           const float* __restrict__ W_pi,
           const float* __restrict__ b_pi,
           float* __restrict__ u,
           unsigned short* __restrict__ vq)
{
    __shared__ float sW[32 * 256];     // 32 KB
    __shared__ float sp1[16 * 64];     //  4 KB

    const int t = threadIdx.x;
    const int wv = t >> 6;
    const int l = t & 63;
    const int atom0 = blockIdx.x * 16;

    #pragma unroll
    for (int f = 0; f < 4; ++f) {
        int idx = f * 256 + t;
        int at = atom0 + (idx >> 6);
        int atc = at < NA ? at : NA - 1;
        sp1[idx] = p1[(size_t)atc * 64 + (idx & 63)];
    }

    float accu[4][4] = {{0}}, accv[4][4] = {{0}};

    #pragma unroll
    for (int s = 0; s < 4; ++s) {
        __syncthreads();
        {
            const float4* src = (const float4*)(W_pi + s * 32 * 256);
            float4* dst = (float4*)sW;
            #pragma unroll
            for (int f = 0; f < 8; ++f) dst[f * 256 + t] = src[f * 256 + t];
        }
        __syncthreads();
        const int kbase = (s & 1) * 32;
        #pragma unroll 2
        for (int k = 0; k < 32; ++k) {
            float4 wq = *(const float4*)&sW[k * 256 + 4 * l];   // cols 4l..4l+3
            #pragma unroll
            for (int a = 0; a < 4; ++a) {
                float pv = sp1[(wv * 4 + a) * 64 + kbase + k];
                if (s < 2) {
                    accu[a][0] = fmaf(pv, wq.x, accu[a][0]);
                    accu[a][1] = fmaf(pv, wq.y, accu[a][1]);
                    accu[a][2] = fmaf(pv, wq.z, accu[a][2]);
                    accu[a][3] = fmaf(pv, wq.w, accu[a][3]);
                } else {
                    accv[a][0] = fmaf(pv, wq.x, accv[a][0]);
                    accv[a][1] = fmaf(pv, wq.y, accv[a][1]);
                    accv[a][2] = fmaf(pv, wq.z, accv[a][2]);
                    accv[a][3] = fmaf(pv, wq.w, accv[a][3]);
                }
            }
        }
    }

    const float4 bp = *(const float4*)&b_pi[4 * l];
    #pragma unroll
    for (int a = 0; a < 4; ++a) {
        const int at = atom0 + wv * 4 + a;
        if (at < NA) {
            float4 uo;
            uo.x = accu[a][0] + bp.x;
            uo.y = accu[a][1] + bp.y;
            uo.z = accu[a][2] + bp.z;
            uo.w = accu[a][3] + bp.w;
            *(float4*)&u[(size_t)at * 256 + 4 * l] = uo;
            uint2 vv;
            vv.x = pack2bf(accv[a][0], accv[a][1]);
            vv.y = pack2bf(accv[a][2], accv[a][3]);
            *(uint2*)&vq[(size_t)at * 512 + 8 * l] = vv;
        }
    }
}

// ---------------------------------------------------------------------------
// K0b (+fused pair count): qi = p3 @ wi_pix -> qi_bf[atom][4l+x];
//                          qj = p3 @ wj_pix -> vq[atom][8l+4..6]  (col l)
// ---------------------------------------------------------------------------
extern "C" __global__ __launch_bounds__(256, 4)
void k0_q(const float* __restrict__ p3,
          const float* __restrict__ wi_pix,
          const float* __restrict__ wj_pix,
          const int* __restrict__ ind2,
          int* __restrict__ cnt,
          unsigned short* __restrict__ qi_bf,
          unsigned short* __restrict__ vq)
{
    __shared__ float sWi[64 * 64];
    __shared__ float sWj[64 * 64];

    const int t = threadIdx.x;

    // fused k_count: first 1954 blocks also count pairs
    {
        int gp = blockIdx.x * 256 + t;
        if (gp < NP) atomicAdd(&cnt[ind2[2 * gp]], 1);
    }

    {
        const float4* si = (const float4*)wi_pix;
        const float4* sj = (const float4*)wj_pix;
        float4* di = (float4*)sWi;
        float4* dj = (float4*)sWj;
        #pragma unroll
        for (int f = 0; f < 4; ++f) { di[f * 256 + t] = si[f * 256 + t]; dj[f * 256 + t] = sj[f * 256 + t]; }
    }
    __syncthreads();

    const int w = t >> 6;
    const int l = t & 63;
    const int atom = blockIdx.x * 4 + w;     // grid 6250 -> < 25000

    float val0 = p3[((size_t)atom * 3 + 0) * 64 + l];
    float val1 = p3[((size_t)atom * 3 + 1) * 64 + l];
    float val2 = p3[((size_t)atom * 3 + 2) * 64 + l];

    float ai[3] = {0, 0, 0}, aj[3] = {0, 0, 0};
    #pragma unroll 8
    for (int k = 0; k < 64; ++k) {
        float a0 = readlane_f(val0, k);
        float a1 = readlane_f(val1, k);
        float a2 = readlane_f(val2, k);
        float wi = sWi[k * 64 + l];
        float wj = sWj[k * 64 + l];
        ai[0] = fmaf(a0, wi, ai[0]); aj[0] = fmaf(a0, wj, aj[0]);
        ai[1] = fmaf(a1, wi, ai[1]); aj[1] = fmaf(a1, wj, aj[1]);
        ai[2] = fmaf(a2, wi, ai[2]); aj[2] = fmaf(a2, wj, aj[2]);
    }
    uint2 iu, ju;
    iu.x = pack2bf(ai[0], ai[1]); iu.y = pack2bf(ai[2], 0.0f);
    ju.x = pack2bf(aj[0], aj[1]); ju.y = pack2bf(aj[2], 0.0f);
    *(uint2*)&qi_bf[(size_t)atom * 256 + 4 * l] = iu;
    *(uint2*)&vq[(size_t)atom * 512 + 8 * l + 4] = ju;
}

// ---------------------------------------------------------------------------
// CSR build
// ---------------------------------------------------------------------------
extern "C" __global__ __launch_bounds__(1024)
void csr_scan(const int* __restrict__ cnt, int* __restrict__ rowstart)
{
    __shared__ int ssum[1024];
    const int t = threadIdx.x;
    const int base = t * 25;

    int s = 0;
    #pragma unroll 5
    for (int i = 0; i < 25; ++i) {
        int idx = base + i;
        s += (idx < NA) ? cnt[idx] : 0;
    }
    ssum[t] = s;
    __syncthreads();
    for (int off = 1; off < 1024; off <<= 1) {
        int vv = (t >= off) ? ssum[t - off] : 0;
        __syncthreads();
        ssum[t] += vv;
        __syncthreads();
    }
    int run = (t > 0) ? ssum[t - 1] : 0;
    for (int i = 0; i < 25; ++i) {
        int idx = base + i;
        if (idx <= NA) rowstart[idx] = run;
        run += (idx < NA) ? cnt[idx] : 0;
    }
}

extern "C" __global__ void k_scatter(const int* __restrict__ ind2,
                                     const int* __restrict__ rowstart,
                                     int* __restrict__ cursor,
                                     int2* __restrict__ plist2)
{
    int p = blockIdx.x * 256 + threadIdx.x;
    if (p < NP) {
        int ii = ind2[2 * p];
        int jj = ind2[2 * p + 1];
        int pos = atomicAdd(&cursor[ii], 1);
        plist2[rowstart[ii] + pos] = make_int2(p, jj);
    }
}

// ---------------------------------------------------------------------------
// K_pair: wave per atom; TWO pairs per iteration; one 16B gather per pair.
// NEW layout: lane l owns h-cols 4l+q -> basis contraction is in-lane
// float4 dot + one xor1 DPP add (6 ops vs 28). pre[c] lives at lanes 2c/2c+1.
// ---------------------------------------------------------------------------
extern "C" __global__ __launch_bounds__(256, 4)
void k_pair(const float* __restrict__ d3,
            const float* __restrict__ basis,
            const float* __restrict__ W_ii,
            const float* __restrict__ u,
            const unsigned short* __restrict__ vq,
            const unsigned short* __restrict__ qi_bf,
            const int* __restrict__ rowstart,
            const int2* __restrict__ plist2,
            float* __restrict__ out_i1,
            float* __restrict__ out_ix,
            float* __restrict__ p1_agg,
            float* __restrict__ p3_agg)
{
    const int t = threadIdx.x;
    const int w = t >> 6;
    const int l = t & 63;
    const int n = blockIdx.x * 4 + w;        // grid 6250*4 = 25000 exactly
    const int boff = 4 * (l & 1);            // basis sub-offset for this lane

    // W_ii columns l (lo) and 64+l (hi) packed as bf16 pairs: 32 VGPRs
    unsigned int wAB[32];
    #pragma unroll
    for (int c = 0; c < 32; ++c)
        wAB[c] = pack2bf(W_ii[c * 128 + l], W_ii[c * 128 + 64 + l]);

    const float4 uu = *(const float4*)&u[(size_t)n * 256 + 4 * l];   // cols 4l+q
    float qiv[3];
    {
        uint2 iu = *(const uint2*)&qi_bf[(size_t)n * 256 + 4 * l];
        qiv[0] = lo_bf(iu.x); qiv[1] = hi_bf(iu.x); qiv[2] = lo_bf(iu.y);
    }

    const int start = rowstart[n];
    const int end   = rowstart[n + 1];

    float agg1a = 0.0f, agg1b = 0.0f;
    float agg30 = 0.0f, agg31 = 0.0f, agg32 = 0.0f;

    if (start < end) {
        const int last = end - 1;

        int2 pj0, pj1;
        uint4 vq0, vq1;
        float4 bs0, bs1;
        float d0x, d0y, d0z, d1x, d1y, d1z;

        {
            int iA = start;
            int iB = (start + 1 <= last) ? start + 1 : last;
            pj0 = plist2[iA];
            pj1 = plist2[iB];
            vq0 = *(const uint4*)&vq[(size_t)pj0.y * 512 + 8 * l];
            vq1 = *(const uint4*)&vq[(size_t)pj1.y * 512 + 8 * l];
            bs0 = *(const float4*)&basis[(size_t)pj0.x * 8 + boff];
            bs1 = *(const float4*)&basis[(size_t)pj1.x * 8 + boff];
            d0x = d3[3 * (size_t)pj0.x + 0]; d0y = d3[3 * (size_t)pj0.x + 1]; d0z = d3[3 * (size_t)pj0.x + 2];
            d1x = d3[3 * (size_t)pj1.x + 0]; d1y = d3[3 * (size_t)pj1.x + 1]; d1z = d3[3 * (size_t)pj1.x + 2];
        }

        for (int it = start; it < end; it += 2) {
            // ---- prefetch next two pairs ----
            int iC = (it + 2 <= last) ? it + 2 : last;
            int iD = (it + 3 <= last) ? it + 3 : last;
            int2 pjT0 = plist2[iC];
            int2 pjT1 = plist2[iD];
            uint4 vqT0 = *(const uint4*)&vq[(size_t)pjT0.y * 512 + 8 * l];
            uint4 vqT1 = *(const uint4*)&vq[(size_t)pjT1.y * 512 + 8 * l];
            float4 bsT0 = *(const float4*)&basis[(size_t)pjT0.x * 8 + boff];
            float4 bsT1 = *(const float4*)&basis[(size_t)pjT1.x * 8 + boff];
            float dT0x = d3[3 * (size_t)pjT0.x + 0];
            float dT0y = d3[3 * (size_t)pjT0.x + 1];
            float dT0z = d3[3 * (size_t)pjT0.x + 2];
            float dT1x = d3[3 * (size_t)pjT1.x + 0];
            float dT1y = d3[3 * (size_t)pjT1.x + 1];
            float dT1z = d3[3 * (size_t)pjT1.x + 2];

            // ---- h = tanh(u+v) for both pairs (cols 4l+q) ----
            float h00 = tanh_fast(uu.x + lo_bf(vq0.x));
            float h10 = tanh_fast(uu.x + lo_bf(vq1.x));
            float h01 = tanh_fast(uu.y + hi_bf(vq0.x));
            float h11 = tanh_fast(uu.y + hi_bf(vq1.x));
            float h02 = tanh_fast(uu.z + lo_bf(vq0.y));
            float h12 = tanh_fast(uu.z + lo_bf(vq1.y));
            float h03 = tanh_fast(uu.w + hi_bf(vq0.y));
            float h13 = tanh_fast(uu.w + hi_bf(vq1.y));

            // ---- basis contraction: in-lane dot4, then xor1 partner add.
            // pre[c = l>>1] lives in lanes 2c and 2c+1.
            float part0 = fmaf(h03, bs0.w, fmaf(h02, bs0.z, fmaf(h01, bs0.y, h00 * bs0.x)));
            float part1 = fmaf(h13, bs1.w, fmaf(h12, bs1.z, fmaf(h11, bs1.y, h10 * bs1.x)));
            float pre0 = dpp_xor1_add(part0);
            float pre1 = dpp_xor1_add(part1);

            // ---- i1 = tanh(pre @ W_ii): broadcast pre[c] from lane 2c ----
            v2f acc0A = {0.0f, 0.0f}, acc0B = {0.0f, 0.0f};
            v2f acc1A = {0.0f, 0.0f}, acc1B = {0.0f, 0.0f};
            #pragma unroll
            for (int c = 0; c < 32; c += 2) {
                float p00 = readlane_f(pre0, 2 * c);
                float p10 = readlane_f(pre1, 2 * c);
                float p01 = readlane_f(pre0, 2 * c + 2);
                float p11 = readlane_f(pre1, 2 * c + 2);
                v2f w0 = w2_bf(wAB[c]);
                v2f w1 = w2_bf(wAB[c + 1]);
                v2f s00 = {p00, p00}, s10 = {p10, p10};
                v2f s01 = {p01, p01}, s11 = {p11, p11};
                acc0A += s00 * w0;
                acc1A += s10 * w0;
                acc0B += s01 * w1;
                acc1B += s11 * w1;
            }
            const float i10_0 = tanh_fast(acc0A.x + acc0B.x);
            const float i11_0 = tanh_fast(acc0A.y + acc0B.y);
            const float i10_1 = tanh_fast(acc1A.x + acc1B.x);
            const float i11_1 = tanh_fast(acc1A.y + acc1B.y);

            // ---- emit pair 0 (always valid) ----
            {
                const size_t pA = (size_t)pj0.x;
                __builtin_nontemporal_store(i10_0, &out_i1[pA * 128 + l]);
                __builtin_nontemporal_store(i11_0, &out_i1[pA * 128 + 64 + l]);
                agg1a += i10_0;
                agg1b += i11_0;
                float ix0 = (qiv[0] + lo_bf(vq0.z) + d0x) * i11_0;
                float ix1 = (qiv[1] + hi_bf(vq0.z) + d0y) * i11_0;
                float ix2 = (qiv[2] + lo_bf(vq0.w) + d0z) * i11_0;
                __builtin_nontemporal_store(ix0, &out_ix[(pA * 3 + 0) * 64 + l]);
                __builtin_nontemporal_store(ix1, &out_ix[(pA * 3 + 1) * 64 + l]);
                __builtin_nontemporal_store(ix2, &out_ix[(pA * 3 + 2) * 64 + l]);
                agg30 += ix0; agg31 += ix1; agg32 += ix2;
            }
            // ---- emit pair 1 (wave-uniform validity) ----
            if (it + 1 < end) {
                const size_t pA = (size_t)pj1.x;
                __builtin_nontemporal_store(i10_1, &out_i1[pA * 128 + l]);
                __builtin_nontemporal_store(i11_1, &out_i1[pA * 128 + 64 + l]);
                agg1a += i10_1;
                agg1b += i11_1;
                float ix0 = (qiv[0] + lo_bf(vq1.z) + d1x) * i11_1;
                float ix1 = (qiv[1] + hi_bf(vq1.z) + d1y) * i11_1;
                float ix2 = (qiv[2] + lo_bf(vq1.w) + d1z) * i11_1;
                __builtin_nontemporal_store(ix0, &out_ix[(pA * 3 + 0) * 64 + l]);
                __builtin_nontemporal_store(ix1, &out_ix[(pA * 3 + 1) * 64 + l]);
                __builtin_nontemporal_store(ix2, &out_ix[(pA * 3 + 2) * 64 + l]);
                agg30 += ix0; agg31 += ix1; agg32 += ix2;
            }

            // rotate
            pj0 = pjT0; vq0 = vqT0; bs0 = bsT0; d0x = dT0x; d0y = dT0y; d0z = dT0z;
            pj1 = pjT1; vq1 = vqT1; bs1 = bsT1; d1x = dT1x; d1y = dT1y; d1z = dT1z;
        }
    }

    p1_agg[(size_t)n * 128 + l]      = agg1a;
    p1_agg[(size_t)n * 128 + 64 + l] = agg1b;
    p3_agg[(size_t)n * 192 + l]       = agg30;
    p3_agg[(size_t)n * 192 + 64 + l]  = agg31;
    p3_agg[(size_t)n * 192 + 128 + l] = agg32;
}

// ---------------------------------------------------------------------------
// K3: per-atom tail.
// ---------------------------------------------------------------------------
extern "C" __global__ __launch_bounds__(256, 4)
void k3_atoms(const float* __restrict__ p1_agg,
              const float* __restrict__ p3_agg,
              const float* __restrict__ W_pp,
              const float* __restrict__ W_ppx,
              const float* __restrict__ wi_dot,
              const float* __restrict__ wj_dot,
              const float* __restrict__ W_pp1,
              const float* __restrict__ b_pp1,
              float* __restrict__ out_p1,
              float* __restrict__ out_p3,
              float* __restrict__ out_dot)
{
    __shared__ float s1[4][128];
    __shared__ float s3[4][192];
    __shared__ float sPm[4][192];
    __shared__ float sCat[4][128];

    const int w = threadIdx.x >> 6;
    const int l = threadIdx.x & 63;
    const int n = blockIdx.x * 4 + w;    // grid = 6250 exactly

    s1[w][l]      = p1_agg[(size_t)n * 128 + l];
    s1[w][64 + l] = p1_agg[(size_t)n * 128 + 64 + l];
    #pragma unroll
    for (int x = 0; x < 3; ++x)
        s3[w][x * 64 + l] = p3_agg[(size_t)n * 192 + x * 64 + l];
    __syncthreads();

    float pn = 0.0f;
    #pragma unroll 4
    for (int k = 0; k < 128; ++k)
        pn = fmaf(s1[w][k], W_pp[k * 64 + l], pn);
    pn = tanh_fast(pn);

    float pm[3];
    #pragma unroll
    for (int x = 0; x < 3; ++x) {
        float s = 0.0f;
        #pragma unroll 4
        for (int c = 0; c < 64; ++c)
            s = fmaf(s3[w][x * 64 + c], W_ppx[c * 64 + l], s);
        pm[x] = s;
        sPm[w][x * 64 + l] = s;
    }
    __syncthreads();

    float dot = 0.0f;
    #pragma unroll
    for (int x = 0; x < 3; ++x) {
        float vi = 0.0f, vj = 0.0f;
        #pragma unroll 4
        for (int c = 0; c < 64; ++c) {
            float a = sPm[w][x * 64 + c];
            vi = fmaf(a, wi_dot[c * 64 + l], vi);
            vj = fmaf(a, wj_dot[c * 64 + l], vj);
        }
        dot = fmaf(vi, vj, dot);
    }

    sCat[w][l]      = pn;
    sCat[w][64 + l] = dot;
    __syncthreads();

    float u1 = b_pp1[l];
    float u2 = b_pp1[64 + l];
    #pragma unroll 4
    for (int k = 0; k < 128; ++k) {
        float ck = sCat[w][k];
        u1 = fmaf(ck, W_pp1[k * 128 + l], u1);
        u2 = fmaf(ck, W_pp1[k * 128 + 64 + l], u2);
    }
    float p1o = tanh_fast(u1);
    float s3v = tanh_fast(u2);

    out_p1[(size_t)n * 64 + l]  = p1o;
    out_dot[(size_t)n * 64 + l] = dot;
    #pragma unroll
    for (int x = 0; x < 3; ++x)
        out_p3[((size_t)n * 3 + x) * 64 + l] = pm[x] * s3v;
}

// ---------------------------------------------------------------------------
extern "C" void kernel_launch(void* const* d_in, const int* in_sizes, int n_in,
                              void* d_out, int out_size, void* d_ws, size_t ws_size,
                              hipStream_t stream)
{
    const int*   ind2   = (const int*)d_in[0];
    const float* p1     = (const float*)d_in[1];
    const float* p3     = (const float*)d_in[2];
    const float* d3     = (const float*)d_in[3];
    const float* basis  = (const float*)d_in[4];
    const float* W_pi   = (const float*)d_in[5];
    const float* b_pi   = (const float*)d_in[6];
    const float* W_ii   = (const float*)d_in[7];
    const float* W_pp   = (const float*)d_in[8];
    const float* wi_pix = (const float*)d_in[9];
    const float* wj_pix = (const float*)d_in[10];
    const float* W_ppx  = (const float*)d_in[11];
    const float* wi_dot = (const float*)d_in[12];
    const float* wj_dot = (const float*)d_in[13];
    const float* W_pp1  = (const float*)d_in[14];
    const float* b_pp1  = (const float*)d_in[15];

    float* out     = (float*)d_out;
    float* out_p1  = out;                      // 25000*64
    float* out_p3  = out + 1600000;            // 25000*192
    float* out_dot = out + 6400000;            // 25000*64
    float* out_i1  = out + 8000000;            // 500000*128
    float* out_ix  = out + 72000000;           // 500000*192

    // workspace (~95MB of the ~2.7GB ws)
    float*          u      = (float*)d_ws;                       // 6,400,000 f32
    unsigned short* vq     = (unsigned short*)(u + 6400000);     // 12,800,000 us (v|qj interleaved)
    unsigned short* qi_bf  = vq + 12800000;                      // 6,400,000 us
    float*          p1_agg = (float*)(qi_bf + 6400000);          // 3,200,000 f32
    float*          p3_agg = p1_agg + 3200000;                   // 4,800,000 f32
    int2*           plist2 = (int2*)(p3_agg + 4800000);          // 500,000 int2 (8B-aligned)
    int*            cnt      = (int*)(plist2 + 500000);          // 25,000
    int*            rowstart = cnt + 25000;                      // 25,001
    int*            cursor   = rowstart + 25001;                 // 25,000

    hipMemsetAsync(cnt, 0, (size_t)75001 * sizeof(int), stream);

    dim3 blk(256);
    k0_uv    <<<dim3(1563), blk, 0, stream>>>(p1, W_pi, b_pi, u, vq);
    k0_q     <<<dim3(6250), blk, 0, stream>>>(p3, wi_pix, wj_pix, ind2, cnt,
                                              qi_bf, vq);
    csr_scan <<<dim3(1), dim3(1024), 0, stream>>>(cnt, rowstart);
    k_scatter<<<dim3(1954), blk, 0, stream>>>(ind2, rowstart, cursor, plist2);
    k_pair   <<<dim3(6250), blk, 0, stream>>>(d3, basis, W_ii, u, vq,
                                              qi_bf, rowstart, plist2,
                                              out_i1, out_ix, p1_agg, p3_agg);
    k3_atoms <<<dim3(6250), blk, 0, stream>>>(p1_agg, p3_agg, W_pp, W_ppx,
                                              wi_dot, wj_dot, W_pp1, b_pp1,
                                              out_p1, out_p3, out_dot);
}

// Round 13
// 557.394 us; speedup vs baseline: 1.3503x; 1.0157x over previous
//
#include <hip/hip_runtime.h>

#define NP 500000
#define NA 25000

typedef float v2f __attribute__((ext_vector_type(2)));

// native-rcp tanh: exp + v_rcp (~1ulp) instead of IEEE divide expansion
__device__ __forceinline__ float tanh_fast(float x) {
    float e = __expf(2.0f * x);
    return 1.0f - __fdividef(2.0f, e + 1.0f);
}

// readlane with float bitcast (__builtin_amdgcn_readlane is (int,int);
// passing float value-converts = truncates — the R2/R3 bug).
__device__ __forceinline__ float readlane_f(float v, int lane) {
    int iv = __builtin_bit_cast(int, v);
    int r = __builtin_amdgcn_readlane(iv, lane);
    return __builtin_bit_cast(float, r);
}

// add value from lane^1 (quad_perm(1,0,3,2) = 0xB1), pure VALU
__device__ __forceinline__ float dpp_xor1_add(float s) {
    int x = __builtin_amdgcn_update_dpp(0, __builtin_bit_cast(int, s), 0xB1, 0xF, 0xF, true);
    return s + __builtin_bit_cast(float, x);
}

__device__ __forceinline__ unsigned short f2bf(float x) {
    union { float f; unsigned int u; } c; c.f = x;
    unsigned int r = c.u + 0x7FFFu + ((c.u >> 16) & 1u);
    return (unsigned short)(r >> 16);
}
__device__ __forceinline__ float bf2f(unsigned short h) {
    union { unsigned int u; float f; } c; c.u = ((unsigned int)h) << 16;
    return c.f;
}
__device__ __forceinline__ unsigned int pack2bf(float a, float b) {
    return (unsigned int)f2bf(a) | ((unsigned int)f2bf(b) << 16);
}
__device__ __forceinline__ float lo_bf(unsigned int x) { return bf2f((unsigned short)(x & 0xffffu)); }
__device__ __forceinline__ float hi_bf(unsigned int x) { return bf2f((unsigned short)(x >> 16)); }
__device__ __forceinline__ float lo_bf_f(unsigned int x) {
    return __builtin_bit_cast(float, x << 16);
}
__device__ __forceinline__ float hi_bf_f(unsigned int x) {
    return __builtin_bit_cast(float, x & 0xffff0000u);
}
// unpack a (lo,hi) bf16 pair into a packed float2 operand
__device__ __forceinline__ v2f w2_bf(unsigned int x) {
    v2f r;
    r.x = lo_bf_f(x);
    r.y = hi_bf_f(x);
    return r;
}

// ---------------------------------------------------------------------------
// K0a: 16 atoms/block.  Lane l computes cols {4l+q} (q=0..3):
//   u[atom][4l+q]  (f32, float4 store)
//   v -> vq[atom][8l+0..3] (bf16), col meaning = 4l+q
// Also zeroes cnt/rowstart/cursor (75,001 ints) — replaces the memset;
// stream-serial with k0_q so the zeroing completes before any atomic.
// ---------------------------------------------------------------------------
extern "C" __global__ __launch_bounds__(256, 2)
void k0_uv(const float* __restrict__ p1,
           const float* __restrict__ W_pi,
           const float* __restrict__ b_pi,
           float* __restrict__ u,
           unsigned short* __restrict__ vq,
           int* __restrict__ zero_base)
{
    __shared__ float sW[32 * 256];     // 32 KB
    __shared__ float sp1[16 * 64];     //  4 KB

    const int t = threadIdx.x;
    const int wv = t >> 6;
    const int l = t & 63;
    const int atom0 = blockIdx.x * 16;

    {
        int gz = blockIdx.x * 256 + t;
        if (gz < 75001) zero_base[gz] = 0;
    }

    #pragma unroll
    for (int f = 0; f < 4; ++f) {
        int idx = f * 256 + t;
        int at = atom0 + (idx >> 6);
        int atc = at < NA ? at : NA - 1;
        sp1[idx] = p1[(size_t)atc * 64 + (idx & 63)];
    }

    float accu[4][4] = {{0}}, accv[4][4] = {{0}};

    #pragma unroll
    for (int s = 0; s < 4; ++s) {
        __syncthreads();
        {
            const float4* src = (const float4*)(W_pi + s * 32 * 256);
            float4* dst = (float4*)sW;
            #pragma unroll
            for (int f = 0; f < 8; ++f) dst[f * 256 + t] = src[f * 256 + t];
        }
        __syncthreads();
        const int kbase = (s & 1) * 32;
        #pragma unroll 2
        for (int k = 0; k < 32; ++k) {
            float4 wq = *(const float4*)&sW[k * 256 + 4 * l];   // cols 4l..4l+3
            #pragma unroll
            for (int a = 0; a < 4; ++a) {
                float pv = sp1[(wv * 4 + a) * 64 + kbase + k];
                if (s < 2) {
                    accu[a][0] = fmaf(pv, wq.x, accu[a][0]);
                    accu[a][1] = fmaf(pv, wq.y, accu[a][1]);
                    accu[a][2] = fmaf(pv, wq.z, accu[a][2]);
                    accu[a][3] = fmaf(pv, wq.w, accu[a][3]);
                } else {
                    accv[a][0] = fmaf(pv, wq.x, accv[a][0]);
                    accv[a][1] = fmaf(pv, wq.y, accv[a][1]);
                    accv[a][2] = fmaf(pv, wq.z, accv[a][2]);
                    accv[a][3] = fmaf(pv, wq.w, accv[a][3]);
                }
            }
        }
    }

    const float4 bp = *(const float4*)&b_pi[4 * l];
    #pragma unroll
    for (int a = 0; a < 4; ++a) {
        const int at = atom0 + wv * 4 + a;
        if (at < NA) {
            float4 uo;
            uo.x = accu[a][0] + bp.x;
            uo.y = accu[a][1] + bp.y;
            uo.z = accu[a][2] + bp.z;
            uo.w = accu[a][3] + bp.w;
            *(float4*)&u[(size_t)at * 256 + 4 * l] = uo;
            uint2 vv;
            vv.x = pack2bf(accv[a][0], accv[a][1]);
            vv.y = pack2bf(accv[a][2], accv[a][3]);
            *(uint2*)&vq[(size_t)at * 512 + 8 * l] = vv;
        }
    }
}

// ---------------------------------------------------------------------------
// K0b (+fused pair count): qi = p3 @ wi_pix -> qi_bf[atom][4l+x];
//                          qj = p3 @ wj_pix -> vq[atom][8l+4..6]  (col l)
// ---------------------------------------------------------------------------
extern "C" __global__ __launch_bounds__(256, 4)
void k0_q(const float* __restrict__ p3,
          const float* __restrict__ wi_pix,
          const float* __restrict__ wj_pix,
          const int* __restrict__ ind2,
          int* __restrict__ cnt,
          unsigned short* __restrict__ qi_bf,
          unsigned short* __restrict__ vq)
{
    __shared__ float sWi[64 * 64];
    __shared__ float sWj[64 * 64];

    const int t = threadIdx.x;

    // fused k_count: first 1954 blocks also count pairs
    {
        int gp = blockIdx.x * 256 + t;
        if (gp < NP) atomicAdd(&cnt[ind2[2 * gp]], 1);
    }

    {
        const float4* si = (const float4*)wi_pix;
        const float4* sj = (const float4*)wj_pix;
        float4* di = (float4*)sWi;
        float4* dj = (float4*)sWj;
        #pragma unroll
        for (int f = 0; f < 4; ++f) { di[f * 256 + t] = si[f * 256 + t]; dj[f * 256 + t] = sj[f * 256 + t]; }
    }
    __syncthreads();

    const int w = t >> 6;
    const int l = t & 63;
    const int atom = blockIdx.x * 4 + w;     // grid 6250 -> < 25000

    float val0 = p3[((size_t)atom * 3 + 0) * 64 + l];
    float val1 = p3[((size_t)atom * 3 + 1) * 64 + l];
    float val2 = p3[((size_t)atom * 3 + 2) * 64 + l];

    float ai[3] = {0, 0, 0}, aj[3] = {0, 0, 0};
    #pragma unroll 8
    for (int k = 0; k < 64; ++k) {
        float a0 = readlane_f(val0, k);
        float a1 = readlane_f(val1, k);
        float a2 = readlane_f(val2, k);
        float wi = sWi[k * 64 + l];
        float wj = sWj[k * 64 + l];
        ai[0] = fmaf(a0, wi, ai[0]); aj[0] = fmaf(a0, wj, aj[0]);
        ai[1] = fmaf(a1, wi, ai[1]); aj[1] = fmaf(a1, wj, aj[1]);
        ai[2] = fmaf(a2, wi, ai[2]); aj[2] = fmaf(a2, wj, aj[2]);
    }
    uint2 iu, ju;
    iu.x = pack2bf(ai[0], ai[1]); iu.y = pack2bf(ai[2], 0.0f);
    ju.x = pack2bf(aj[0], aj[1]); ju.y = pack2bf(aj[2], 0.0f);
    *(uint2*)&qi_bf[(size_t)atom * 256 + 4 * l] = iu;
    *(uint2*)&vq[(size_t)atom * 512 + 8 * l + 4] = ju;
}

// ---------------------------------------------------------------------------
// CSR build
// ---------------------------------------------------------------------------
extern "C" __global__ __launch_bounds__(1024)
void csr_scan(const int* __restrict__ cnt, int* __restrict__ rowstart)
{
    __shared__ int ssum[1024];
    const int t = threadIdx.x;
    const int base = t * 25;

    int s = 0;
    #pragma unroll 5
    for (int i = 0; i < 25; ++i) {
        int idx = base + i;
        s += (idx < NA) ? cnt[idx] : 0;
    }
    ssum[t] = s;
    __syncthreads();
    for (int off = 1; off < 1024; off <<= 1) {
        int vv = (t >= off) ? ssum[t - off] : 0;
        __syncthreads();
        ssum[t] += vv;
        __syncthreads();
    }
    int run = (t > 0) ? ssum[t - 1] : 0;
    for (int i = 0; i < 25; ++i) {
        int idx = base + i;
        if (idx <= NA) rowstart[idx] = run;
        run += (idx < NA) ? cnt[idx] : 0;
    }
}

extern "C" __global__ void k_scatter(const int* __restrict__ ind2,
                                     const int* __restrict__ rowstart,
                                     int* __restrict__ cursor,
                                     int2* __restrict__ plist2)
{
    int p = blockIdx.x * 256 + threadIdx.x;
    if (p < NP) {
        int ii = ind2[2 * p];
        int jj = ind2[2 * p + 1];
        int pos = atomicAdd(&cursor[ii], 1);
        plist2[rowstart[ii] + pos] = make_int2(p, jj);
    }
}

// ---------------------------------------------------------------------------
// K_pair: wave per atom; TWO pairs per iteration; one 16B gather per pair.
// Lane l owns h-cols 4l+q; basis contraction = in-lane dot4 + xor1 DPP add.
// FUSED per-atom tail (ex-k3): runs per-wave on private LDS rows — no
// __syncthreads needed (each wave only touches s*[w][...]).
// ---------------------------------------------------------------------------
extern "C" __global__ __launch_bounds__(256, 4)
void k_pair(const float* __restrict__ d3,
            const float* __restrict__ basis,
            const float* __restrict__ W_ii,
            const float* __restrict__ u,
            const unsigned short* __restrict__ vq,
            const unsigned short* __restrict__ qi_bf,
            const int* __restrict__ rowstart,
            const int2* __restrict__ plist2,
            const float* __restrict__ W_pp,
            const float* __restrict__ W_ppx,
            const float* __restrict__ wi_dot,
            const float* __restrict__ wj_dot,
            const float* __restrict__ W_pp1,
            const float* __restrict__ b_pp1,
            float* __restrict__ out_i1,
            float* __restrict__ out_ix,
            float* __restrict__ out_p1,
            float* __restrict__ out_p3,
            float* __restrict__ out_dot)
{
    __shared__ float s1[4][128];
    __shared__ float s3[4][192];
    __shared__ float sPm[4][192];
    __shared__ float sCat[4][128];

    const int t = threadIdx.x;
    const int w = t >> 6;
    const int l = t & 63;
    const int n = blockIdx.x * 4 + w;        // grid 6250*4 = 25000 exactly
    const int boff = 4 * (l & 1);            // basis sub-offset for this lane

    // W_ii columns l (lo) and 64+l (hi) packed as bf16 pairs: 32 VGPRs
    unsigned int wAB[32];
    #pragma unroll
    for (int c = 0; c < 32; ++c)
        wAB[c] = pack2bf(W_ii[c * 128 + l], W_ii[c * 128 + 64 + l]);

    const float4 uu = *(const float4*)&u[(size_t)n * 256 + 4 * l];   // cols 4l+q
    float qiv[3];
    {
        uint2 iu = *(const uint2*)&qi_bf[(size_t)n * 256 + 4 * l];
        qiv[0] = lo_bf(iu.x); qiv[1] = hi_bf(iu.x); qiv[2] = lo_bf(iu.y);
    }

    const int start = rowstart[n];
    const int end   = rowstart[n + 1];

    float agg1a = 0.0f, agg1b = 0.0f;
    float agg30 = 0.0f, agg31 = 0.0f, agg32 = 0.0f;

    if (start < end) {
        const int last = end - 1;

        int2 pj0, pj1;
        uint4 vq0, vq1;
        float4 bs0, bs1;
        float d0x, d0y, d0z, d1x, d1y, d1z;

        {
            int iA = start;
            int iB = (start + 1 <= last) ? start + 1 : last;
            pj0 = plist2[iA];
            pj1 = plist2[iB];
            vq0 = *(const uint4*)&vq[(size_t)pj0.y * 512 + 8 * l];
            vq1 = *(const uint4*)&vq[(size_t)pj1.y * 512 + 8 * l];
            bs0 = *(const float4*)&basis[(size_t)pj0.x * 8 + boff];
            bs1 = *(const float4*)&basis[(size_t)pj1.x * 8 + boff];
            d0x = d3[3 * (size_t)pj0.x + 0]; d0y = d3[3 * (size_t)pj0.x + 1]; d0z = d3[3 * (size_t)pj0.x + 2];
            d1x = d3[3 * (size_t)pj1.x + 0]; d1y = d3[3 * (size_t)pj1.x + 1]; d1z = d3[3 * (size_t)pj1.x + 2];
        }

        for (int it = start; it < end; it += 2) {
            // ---- prefetch next two pairs ----
            int iC = (it + 2 <= last) ? it + 2 : last;
            int iD = (it + 3 <= last) ? it + 3 : last;
            int2 pjT0 = plist2[iC];
            int2 pjT1 = plist2[iD];
            uint4 vqT0 = *(const uint4*)&vq[(size_t)pjT0.y * 512 + 8 * l];
            uint4 vqT1 = *(const uint4*)&vq[(size_t)pjT1.y * 512 + 8 * l];
            float4 bsT0 = *(const float4*)&basis[(size_t)pjT0.x * 8 + boff];
            float4 bsT1 = *(const float4*)&basis[(size_t)pjT1.x * 8 + boff];
            float dT0x = d3[3 * (size_t)pjT0.x + 0];
            float dT0y = d3[3 * (size_t)pjT0.x + 1];
            float dT0z = d3[3 * (size_t)pjT0.x + 2];
            float dT1x = d3[3 * (size_t)pjT1.x + 0];
            float dT1y = d3[3 * (size_t)pjT1.x + 1];
            float dT1z = d3[3 * (size_t)pjT1.x + 2];

            // ---- h = tanh(u+v) for both pairs (cols 4l+q) ----
            float h00 = tanh_fast(uu.x + lo_bf(vq0.x));
            float h10 = tanh_fast(uu.x + lo_bf(vq1.x));
            float h01 = tanh_fast(uu.y + hi_bf(vq0.x));
            float h11 = tanh_fast(uu.y + hi_bf(vq1.x));
            float h02 = tanh_fast(uu.z + lo_bf(vq0.y));
            float h12 = tanh_fast(uu.z + lo_bf(vq1.y));
            float h03 = tanh_fast(uu.w + hi_bf(vq0.y));
            float h13 = tanh_fast(uu.w + hi_bf(vq1.y));

            // ---- basis contraction: in-lane dot4, then xor1 partner add ----
            float part0 = fmaf(h03, bs0.w, fmaf(h02, bs0.z, fmaf(h01, bs0.y, h00 * bs0.x)));
            float part1 = fmaf(h13, bs1.w, fmaf(h12, bs1.z, fmaf(h11, bs1.y, h10 * bs1.x)));
            float pre0 = dpp_xor1_add(part0);
            float pre1 = dpp_xor1_add(part1);

            // ---- i1 = tanh(pre @ W_ii): broadcast pre[c] from lane 2c ----
            v2f acc0A = {0.0f, 0.0f}, acc0B = {0.0f, 0.0f};
            v2f acc1A = {0.0f, 0.0f}, acc1B = {0.0f, 0.0f};
            #pragma unroll
            for (int c = 0; c < 32; c += 2) {
                float p00 = readlane_f(pre0, 2 * c);
                float p10 = readlane_f(pre1, 2 * c);
                float p01 = readlane_f(pre0, 2 * c + 2);
                float p11 = readlane_f(pre1, 2 * c + 2);
                v2f w0 = w2_bf(wAB[c]);
                v2f w1 = w2_bf(wAB[c + 1]);
                v2f s00 = {p00, p00}, s10 = {p10, p10};
                v2f s01 = {p01, p01}, s11 = {p11, p11};
                acc0A += s00 * w0;
                acc1A += s10 * w0;
                acc0B += s01 * w1;
                acc1B += s11 * w1;
            }
            const float i10_0 = tanh_fast(acc0A.x + acc0B.x);
            const float i11_0 = tanh_fast(acc0A.y + acc0B.y);
            const float i10_1 = tanh_fast(acc1A.x + acc1B.x);
            const float i11_1 = tanh_fast(acc1A.y + acc1B.y);

            // ---- emit pair 0 (always valid) ----
            {
                const size_t pA = (size_t)pj0.x;
                __builtin_nontemporal_store(i10_0, &out_i1[pA * 128 + l]);
                __builtin_nontemporal_store(i11_0, &out_i1[pA * 128 + 64 + l]);
                agg1a += i10_0;
                agg1b += i11_0;
                float ix0 = (qiv[0] + lo_bf(vq0.z) + d0x) * i11_0;
                float ix1 = (qiv[1] + hi_bf(vq0.z) + d0y) * i11_0;
                float ix2 = (qiv[2] + lo_bf(vq0.w) + d0z) * i11_0;
                __builtin_nontemporal_store(ix0, &out_ix[(pA * 3 + 0) * 64 + l]);
                __builtin_nontemporal_store(ix1, &out_ix[(pA * 3 + 1) * 64 + l]);
                __builtin_nontemporal_store(ix2, &out_ix[(pA * 3 + 2) * 64 + l]);
                agg30 += ix0; agg31 += ix1; agg32 += ix2;
            }
            // ---- emit pair 1 (wave-uniform validity) ----
            if (it + 1 < end) {
                const size_t pA = (size_t)pj1.x;
                __builtin_nontemporal_store(i10_1, &out_i1[pA * 128 + l]);
                __builtin_nontemporal_store(i11_1, &out_i1[pA * 128 + 64 + l]);
                agg1a += i10_1;
                agg1b += i11_1;
                float ix0 = (qiv[0] + lo_bf(vq1.z) + d1x) * i11_1;
                float ix1 = (qiv[1] + hi_bf(vq1.z) + d1y) * i11_1;
                float ix2 = (qiv[2] + lo_bf(vq1.w) + d1z) * i11_1;
                __builtin_nontemporal_store(ix0, &out_ix[(pA * 3 + 0) * 64 + l]);
                __builtin_nontemporal_store(ix1, &out_ix[(pA * 3 + 1) * 64 + l]);
                __builtin_nontemporal_store(ix2, &out_ix[(pA * 3 + 2) * 64 + l]);
                agg30 += ix0; agg31 += ix1; agg32 += ix2;
            }

            // rotate
            pj0 = pjT0; vq0 = vqT0; bs0 = bsT0; d0x = dT0x; d0y = dT0y; d0z = dT0z;
            pj1 = pjT1; vq1 = vqT1; bs1 = bsT1; d1x = dT1x; d1y = dT1y; d1z = dT1z;
        }
    }

    // ======================= fused per-atom tail (ex-k3) ====================
    // Each wave uses only its own LDS row s*[w][...]: within-wave LDS RAW is
    // ordered by lgkmcnt (compiler-inserted) — no __syncthreads needed.
    s1[w][l]       = agg1a;
    s1[w][64 + l]  = agg1b;
    s3[w][l]       = agg30;
    s3[w][64 + l]  = agg31;
    s3[w][128 + l] = agg32;

    // p1_new = tanh(p1_agg @ W_pp)
    float pn = 0.0f;
    #pragma unroll 4
    for (int k = 0; k < 128; ++k)
        pn = fmaf(s1[w][k], W_pp[k * 64 + l], pn);
    pn = tanh_fast(pn);

    // p3_mixed = p3_agg @ W_ppx
    float pm[3];
    #pragma unroll
    for (int x = 0; x < 3; ++x) {
        float s = 0.0f;
        #pragma unroll 4
        for (int c = 0; c < 64; ++c)
            s = fmaf(s3[w][x * 64 + c], W_ppx[c * 64 + l], s);
        pm[x] = s;
        sPm[w][x * 64 + l] = s;
    }

    // dotted = sum_x (pm@wi_dot)*(pm@wj_dot)
    float dot = 0.0f;
    #pragma unroll
    for (int x = 0; x < 3; ++x) {
        float vi = 0.0f, vj = 0.0f;
        #pragma unroll 4
        for (int c = 0; c < 64; ++c) {
            float a = sPm[w][x * 64 + c];
            vi = fmaf(a, wi_dot[c * 64 + l], vi);
            vj = fmaf(a, wj_dot[c * 64 + l], vj);
        }
        dot = fmaf(vi, vj, dot);
    }

    sCat[w][l]      = pn;
    sCat[w][64 + l] = dot;

    float u1 = b_pp1[l];
    float u2 = b_pp1[64 + l];
    #pragma unroll 4
    for (int k = 0; k < 128; ++k) {
        float ck = sCat[w][k];
        u1 = fmaf(ck, W_pp1[k * 128 + l], u1);
        u2 = fmaf(ck, W_pp1[k * 128 + 64 + l], u2);
    }
    float p1o = tanh_fast(u1);
    float s3v = tanh_fast(u2);

    out_p1[(size_t)n * 64 + l]  = p1o;
    out_dot[(size_t)n * 64 + l] = dot;
    #pragma unroll
    for (int x = 0; x < 3; ++x)
        out_p3[((size_t)n * 3 + x) * 64 + l] = pm[x] * s3v;
}

// ---------------------------------------------------------------------------
extern "C" void kernel_launch(void* const* d_in, const int* in_sizes, int n_in,
                              void* d_out, int out_size, void* d_ws, size_t ws_size,
                              hipStream_t stream)
{
    const int*   ind2   = (const int*)d_in[0];
    const float* p1     = (const float*)d_in[1];
    const float* p3     = (const float*)d_in[2];
    const float* d3     = (const float*)d_in[3];
    const float* basis  = (const float*)d_in[4];
    const float* W_pi   = (const float*)d_in[5];
    const float* b_pi   = (const float*)d_in[6];
    const float* W_ii   = (const float*)d_in[7];
    const float* W_pp   = (const float*)d_in[8];
    const float* wi_pix = (const float*)d_in[9];
    const float* wj_pix = (const float*)d_in[10];
    const float* W_ppx  = (const float*)d_in[11];
    const float* wi_dot = (const float*)d_in[12];
    const float* wj_dot = (const float*)d_in[13];
    const float* W_pp1  = (const float*)d_in[14];
    const float* b_pp1  = (const float*)d_in[15];

    float* out     = (float*)d_out;
    float* out_p1  = out;                      // 25000*64
    float* out_p3  = out + 1600000;            // 25000*192
    float* out_dot = out + 6400000;            // 25000*64
    float* out_i1  = out + 8000000;            // 500000*128
    float* out_ix  = out + 72000000;           // 500000*192

    // workspace (~70MB of the ~2.7GB ws)
    float*          u      = (float*)d_ws;                       // 6,400,000 f32
    unsigned short* vq     = (unsigned short*)(u + 6400000);     // 12,800,000 us (v|qj interleaved)
    unsigned short* qi_bf  = vq + 12800000;                      // 6,400,000 us
    int2*           plist2 = (int2*)(qi_bf + 6400000);           // 500,000 int2 (8B-aligned)
    int*            cnt      = (int*)(plist2 + 500000);          // 25,000
    int*            rowstart = cnt + 25000;                      // 25,001
    int*            cursor   = rowstart + 25001;                 // 25,000

    dim3 blk(256);
    k0_uv    <<<dim3(1563), blk, 0, stream>>>(p1, W_pi, b_pi, u, vq, cnt);
    k0_q     <<<dim3(6250), blk, 0, stream>>>(p3, wi_pix, wj_pix, ind2, cnt,
                                              qi_bf, vq);
    csr_scan <<<dim3(1), dim3(1024), 0, stream>>>(cnt, rowstart);
    k_scatter<<<dim3(1954), blk, 0, stream>>>(ind2, rowstart, cursor, plist2);
    k_pair   <<<dim3(6250), blk, 0, stream>>>(d3, basis, W_ii, u, vq,
                                              qi_bf, rowstart, plist2,
                                              W_pp, W_ppx, wi_dot, wj_dot,
                                              W_pp1, b_pp1,
                                              out_i1, out_ix,
                                              out_p1, out_p3, out_dot);
}